// Round 10
// baseline (254.887 us; speedup 1.0000x reference)
//
#include <hip/hip_runtime.h>

#define LRELU(x) ((x) > 0.f ? (x) : 0.2f*(x))
typedef unsigned int uint;
typedef unsigned short ushort;

__device__ inline ushort f2bf(float f) {
    union { float f; unsigned u; } v; v.f = f;
    unsigned r = v.u + 0x7FFF + ((v.u >> 16) & 1);
    return (ushort)(r >> 16);
}
__device__ inline uint packbf(float a, float b) {
    return (uint)f2bf(a) | ((uint)f2bf(b) << 16);
}
__device__ inline float bflo(uint u){ union{uint u; float f;}v; v.u = u<<16; return v.f; }
__device__ inline float bfhi(uint u){ union{uint u; float f;}v; v.u = u & 0xFFFF0000u; return v.f; }

// ---------------- CSR build: atomic-free two-level bucket sort ----------------
// ebuf entries packed: (src << 7) | (dst & 127)

#define CSR_SHIFT 7
#define CSR_NBLK  512

__global__ __launch_bounds__(256) void bucket_count_kernel(
    const int* __restrict__ dst, int E, int chunk, int nb,
    int* __restrict__ blockCntT)
{
    __shared__ int cnt[1024];
    int t = threadIdx.x, k = blockIdx.x;
    for (int i = t; i < nb; i += 256) cnt[i] = 0;
    __syncthreads();
    int e0 = k * chunk, e1 = min(e0 + chunk, E);
    for (int e = e0 + t; e < e1; e += 256)
        atomicAdd(&cnt[dst[e] >> CSR_SHIFT], 1);
    __syncthreads();
    for (int b = t; b < nb; b += 256)
        blockCntT[b * CSR_NBLK + k] = cnt[b];
}

// Per-bucket scan across chunks; last block also scans bucket totals.
__global__ __launch_bounds__(512) void row_scan_kernel(
    int* __restrict__ blockCntT, int* __restrict__ tot,
    int* __restrict__ bucketBase, int nb, int* __restrict__ done)
{
    __shared__ int sm[512];
    __shared__ int isLast;
    int b = blockIdx.x, t = threadIdx.x;
    int* row = blockCntT + b * CSR_NBLK;
    int v = row[t];
    sm[t] = v;
    __syncthreads();
    for (int off = 1; off < 512; off <<= 1) {
        int u = (t >= off) ? sm[t - off] : 0;
        __syncthreads(); sm[t] += u; __syncthreads();
    }
    row[t] = sm[t] - v;            // exclusive within bucket
    if (t == 511) tot[b] = sm[511];
    __threadfence();
    if (t == 0) isLast = (atomicAdd(done, 1) == gridDim.x - 1);
    __syncthreads();
    if (isLast) {
        __threadfence();
        int w = (t < nb) ? tot[t] : 0;
        sm[t] = w;
        __syncthreads();
        for (int off = 1; off < 512; off <<= 1) {
            int u = (t >= off) ? sm[t - off] : 0;
            __syncthreads(); sm[t] += u; __syncthreads();
        }
        if (t < nb) bucketBase[t] = sm[t] - w;
        if (t == 511) bucketBase[nb] = sm[511];
    }
}

__global__ __launch_bounds__(256) void bucket_scatter_kernel(
    const int* __restrict__ src, const int* __restrict__ dst, int E, int chunk, int nb,
    const int* __restrict__ blockCntT, const int* __restrict__ bucketBase,
    uint* __restrict__ ebuf)
{
    __shared__ int cur[1024];
    int t = threadIdx.x, k = blockIdx.x;
    for (int b = t; b < nb; b += 256)
        cur[b] = bucketBase[b] + blockCntT[b * CSR_NBLK + k];
    __syncthreads();
    int e0 = k * chunk, e1 = min(e0 + chunk, E);
    for (int e = e0 + t; e < e1; e += 256) {
        int d = dst[e], s_ = src[e];
        int pos = atomicAdd(&cur[d >> CSR_SHIFT], 1);
        ebuf[pos] = ((uint)s_ << 7) | (uint)(d & 127);
    }
}

__global__ __launch_bounds__(256) void local_csr_kernel(
    const uint* __restrict__ ebuf, const int* __restrict__ bucketBase,
    int n, int E, int* __restrict__ rowptr, int* __restrict__ csr)
{
    __shared__ int lbase[1 << CSR_SHIFT];
    __shared__ int lcur[1 << CSR_SHIFT];
    __shared__ int ldeg[1 << CSR_SHIFT];
    int b = blockIdx.x, t = threadIdx.x;
    int n0 = b << CSR_SHIFT;
    int base = bucketBase[b], end = bucketBase[b + 1];
    if (t < (1 << CSR_SHIFT)) ldeg[t] = 0;
    __syncthreads();
    for (int e = base + t; e < end; e += 256)
        atomicAdd(&ldeg[ebuf[e] & 127], 1);
    __syncthreads();
    if (t == 0) {
        int run = base;
        for (int i = 0; i < (1 << CSR_SHIFT); ++i) {
            lbase[i] = run; lcur[i] = run; run += ldeg[i];
        }
    }
    __syncthreads();
    int node = n0 + t;
    if (t < (1 << CSR_SHIFT) && node < n) rowptr[node] = lbase[t];
    if (b == 0 && t == 0) rowptr[n] = E;
    for (int e = base + t; e < end; e += 256) {
        uint ed = ebuf[e];
        int pos = atomicAdd(&lcur[ed & 127], 1);
        csr[pos] = (int)(ed >> 7);
    }
}

// ---------------- GEMM + fused alpha dots ----------------
// NPT=4 nodes/thread. XBF16: input rows are bf16 (n x COLSIN packed u32 pairs).
// COLS=128 -> fp8 e4m3 output; COLS=32 -> bf16 output.

template<int COLS, int HEADS, bool XBF16>
__global__ __launch_bounds__(256) void gemm_alpha_kernel(
    const void* __restrict__ xin, const float* __restrict__ W,
    const float* __restrict__ a_src, const float* __restrict__ a_dst,
    uint* __restrict__ hq, float* __restrict__ as_out,
    float* __restrict__ ad_out, int n)
{
    constexpr int K = 128;
    constexpr int CPT = COLS / 8;
    constexpr int NPT = 4;
    constexpr int DIM = COLS / HEADS;
    constexpr int TPH = DIM / CPT;
    constexpr int NSLOT = COLS / 4;
    __shared__ float4 WL[K * NSLOT];

    int t = threadIdx.x;
    for (int idx = t * 4; idx < K * COLS; idx += 1024) {
        float4 w = *(const float4*)(W + idx);
        int k = idx / COLS, c = idx % COLS;
        int slot = c >> 2;
        if (COLS == 128) slot = (slot >> 2) | ((slot & 3) << 3);
        WL[k * NSLOT + slot] = w;
    }
    __syncthreads();

    int m_ = t & 7;
    int node0 = blockIdx.x * (32 * NPT) + (t >> 3) * NPT;
    if (node0 >= n) return;
    int c0 = m_ * CPT;

    size_t rows[NPT];
#pragma unroll
    for (int i = 0; i < NPT; i++) rows[i] = (size_t)min(node0 + i, n - 1);

    float acc[NPT][CPT];
#pragma unroll
    for (int i = 0; i < NPT; i++)
#pragma unroll
        for (int q = 0; q < CPT; q++) acc[i][q] = 0.f;

    for (int k4 = 0; k4 < K; k4 += 4) {
        float xs[NPT][4];
#pragma unroll
        for (int i = 0; i < NPT; i++) {
            if constexpr (XBF16) {
                uint2 u = *(const uint2*)((const uint*)xin + rows[i] * 64 + (k4 >> 1));
                xs[i][0] = bflo(u.x); xs[i][1] = bfhi(u.x);
                xs[i][2] = bflo(u.y); xs[i][3] = bfhi(u.y);
            } else {
                float4 v = *(const float4*)((const float*)xin + rows[i] * 128 + k4);
                xs[i][0] = v.x; xs[i][1] = v.y; xs[i][2] = v.z; xs[i][3] = v.w;
            }
        }
#pragma unroll
        for (int kk = 0; kk < 4; kk++) {
#pragma unroll
            for (int j = 0; j < CPT / 4; j++) {
                int slot = (COLS == 128) ? (m_ | (j << 3)) : m_;
                float4 w = WL[(k4 + kk) * NSLOT + slot];
#pragma unroll
                for (int i = 0; i < NPT; i++) {
                    float xa = xs[i][kk];
                    acc[i][j*4+0] += xa * w.x;
                    acc[i][j*4+1] += xa * w.y;
                    acc[i][j*4+2] += xa * w.z;
                    acc[i][j*4+3] += xa * w.w;
                }
            }
        }
    }

    int head = c0 / DIM, lc = c0 - head * DIM;
    float asc[CPT], adc[CPT];
#pragma unroll
    for (int q = 0; q < CPT; q++) {
        asc[q] = a_src[head * DIM + lc + q];
        adc[q] = a_dst[head * DIM + lc + q];
    }

#pragma unroll
    for (int i = 0; i < NPT; i++) {
        int node = node0 + i;
        if (node >= n) break;
        if constexpr (COLS == 128) {
            uint wds[4];
#pragma unroll
            for (int j = 0; j < 4; j++) {
                int u = 0;
                u = __builtin_amdgcn_cvt_pk_fp8_f32(acc[i][j*4+0], acc[i][j*4+1], u, false);
                u = __builtin_amdgcn_cvt_pk_fp8_f32(acc[i][j*4+2], acc[i][j*4+3], u, true);
                wds[j] = (uint)u;
            }
            *(uint4*)(hq + (size_t)node * 32 + m_ * 4) = make_uint4(wds[0], wds[1], wds[2], wds[3]);
        } else {
            uint w0 = packbf(acc[i][0], acc[i][1]);
            uint w1 = packbf(acc[i][2], acc[i][3]);
            *(uint2*)(hq + (size_t)node * 16 + m_ * 2) = make_uint2(w0, w1);
        }
        float ps = 0.f, pd = 0.f;
#pragma unroll
        for (int q = 0; q < CPT; q++) {
            ps += acc[i][q] * asc[q];
            pd += acc[i][q] * adc[q];
        }
#pragma unroll
        for (int off = 1; off < TPH; off <<= 1) {
            ps += __shfl_xor(ps, off);
            pd += __shfl_xor(pd, off);
        }
        if ((m_ & (TPH - 1)) == 0) {
            as_out[node * HEADS + head] = ps;
            ad_out[node * HEADS + head] = pd;
        }
    }
}

// ---------------- Layer-1 aggregation (flat, fp8 gather) ----------------
// One wave per node; no LDS/barriers. 8 groups x 8 lanes; group g owns edges
// rp+g+8k. Lane: head=l>>1, dims 16l..16l+15 (uint4 = 16 fp8). Non-temporal
// csr stream read preserves L2 for the h1q table. Output hrelu in bf16.

__global__ __launch_bounds__(256) void agg1_kernel(
    const float* __restrict__ as1f, const float* __restrict__ ad1f,
    const uint* __restrict__ h1q, const int* __restrict__ rowptr,
    const int* __restrict__ csr, const float* __restrict__ b1,
    uint* __restrict__ hrelu, int n)
{
    int t = threadIdx.x;
    int w = t >> 6, tw = t & 63;
    int g = tw >> 3, l = tw & 7;   // 8 groups x 8 lanes
    int head = l >> 1;
    int node = blockIdx.x * 4 + w;
    if (node >= n) return;

    float adh = ad1f[node * 4 + head];
    int rp = rowptr[node], re = rowptr[node + 1];

    float acc[16];
#pragma unroll
    for (int i = 0; i < 16; i++) acc[i] = 0.f;
    float den = 0.f;

#pragma unroll 2
    for (int e = rp + g; e < re; e += 8) {
        int s = __builtin_nontemporal_load(csr + e);
        float a = as1f[s * 4 + head];
        uint4 u = *(const uint4*)(h1q + ((size_t)s << 5) + (l << 2));
        float ex = __expf(LRELU(a + adh));
        den += ex;
        uint ua[4] = {u.x, u.y, u.z, u.w};
#pragma unroll
        for (int j = 0; j < 4; j++) {
            auto p0 = __builtin_amdgcn_cvt_pk_f32_fp8(ua[j], false);
            auto p1 = __builtin_amdgcn_cvt_pk_f32_fp8(ua[j], true);
            acc[j*4+0] += ex * p0[0]; acc[j*4+1] += ex * p0[1];
            acc[j*4+2] += ex * p1[0]; acc[j*4+3] += ex * p1[1];
        }
    }

    if (g == 0) {   // self loop, counted once (pre-reduction)
        float a = as1f[node * 4 + head];
        float ex = __expf(LRELU(a + adh));
        den += ex;
        uint4 u = *(const uint4*)(h1q + ((size_t)node << 5) + (l << 2));
        uint ua[4] = {u.x, u.y, u.z, u.w};
#pragma unroll
        for (int j = 0; j < 4; j++) {
            auto p0 = __builtin_amdgcn_cvt_pk_f32_fp8(ua[j], false);
            auto p1 = __builtin_amdgcn_cvt_pk_f32_fp8(ua[j], true);
            acc[j*4+0] += ex * p0[0]; acc[j*4+1] += ex * p0[1];
            acc[j*4+2] += ex * p1[0]; acc[j*4+3] += ex * p1[1];
        }
    }

    // reduce across the 8 groups (lane-id bits 3,4,5)
#pragma unroll
    for (int i = 0; i < 16; i++) {
        acc[i] += __shfl_xor(acc[i], 8);
        acc[i] += __shfl_xor(acc[i], 16);
        acc[i] += __shfl_xor(acc[i], 32);
    }
    den += __shfl_xor(den, 8);
    den += __shfl_xor(den, 16);
    den += __shfl_xor(den, 32);

    if (g == 0) {
        float inv = 1.f / (den + 1e-16f);
        uint o[8];
#pragma unroll
        for (int j = 0; j < 4; j++) {
            float v0 = fmaxf(acc[j*4+0] * inv + b1[16*l + 4*j + 0], 0.f);
            float v1 = fmaxf(acc[j*4+1] * inv + b1[16*l + 4*j + 1], 0.f);
            float v2 = fmaxf(acc[j*4+2] * inv + b1[16*l + 4*j + 2], 0.f);
            float v3 = fmaxf(acc[j*4+3] * inv + b1[16*l + 4*j + 3], 0.f);
            o[2*j]   = packbf(v0, v1);
            o[2*j+1] = packbf(v2, v3);
        }
        uint* hp = hrelu + (size_t)node * 64 + l * 8;
        *(uint4*)hp       = make_uint4(o[0], o[1], o[2], o[3]);
        *(uint4*)(hp + 4) = make_uint4(o[4], o[5], o[6], o[7]);
    }
}

// ---------------- Layer-2 aggregation (flat, bf16 gather, head-mean) ----------

__global__ __launch_bounds__(256) void agg2_kernel(
    const float* __restrict__ as2f, const float* __restrict__ ad2f,
    const uint* __restrict__ h2q, const int* __restrict__ rowptr,
    const int* __restrict__ csr, const float* __restrict__ b2,
    float* __restrict__ hf, int n)
{
    int t = threadIdx.x;
    int w = t >> 6, tw = t & 63;
    int g = tw >> 3, l = tw & 7;
    int head = l >> 2;
    int node = blockIdx.x * 4 + w;
    if (node >= n) return;

    float adh = ad2f[node * 2 + head];
    int rp = rowptr[node], re = rowptr[node + 1];

    float acc[4] = {0.f, 0.f, 0.f, 0.f};
    float den = 0.f;

#pragma unroll 2
    for (int e = rp + g; e < re; e += 8) {
        int s = __builtin_nontemporal_load(csr + e);
        float a = as2f[s * 2 + head];
        uint2 u = *(const uint2*)(h2q + ((size_t)s << 4) + (l << 1));
        float ex = __expf(LRELU(a + adh));
        den += ex;
        acc[0] += ex * bflo(u.x); acc[1] += ex * bfhi(u.x);
        acc[2] += ex * bflo(u.y); acc[3] += ex * bfhi(u.y);
    }

    if (g == 0) {   // self loop
        float a = as2f[node * 2 + head];
        float ex = __expf(LRELU(a + adh));
        den += ex;
        uint2 u = *(const uint2*)(h2q + ((size_t)node << 4) + (l << 1));
        acc[0] += ex * bflo(u.x); acc[1] += ex * bfhi(u.x);
        acc[2] += ex * bflo(u.y); acc[3] += ex * bfhi(u.y);
    }

#pragma unroll
    for (int i = 0; i < 4; i++) {
        acc[i] += __shfl_xor(acc[i], 8);
        acc[i] += __shfl_xor(acc[i], 16);
        acc[i] += __shfl_xor(acc[i], 32);
    }
    den += __shfl_xor(den, 8);
    den += __shfl_xor(den, 16);
    den += __shfl_xor(den, 32);

    float inv = 1.f / (den + 1e-16f);
    float v0 = acc[0] * inv, v1 = acc[1] * inv, v2 = acc[2] * inv, v3 = acc[3] * inv;
    // mean over heads: lane l (head0, dims 4l..) pairs with lane l^4 (head1)
    float o0 = 0.5f * (v0 + __shfl_xor(v0, 4));
    float o1 = 0.5f * (v1 + __shfl_xor(v1, 4));
    float o2 = 0.5f * (v2 + __shfl_xor(v2, 4));
    float o3 = 0.5f * (v3 + __shfl_xor(v3, 4));
    if (g == 0 && l < 4) {
        float4 o;
        o.x = o0 + b2[4*l+0]; o.y = o1 + b2[4*l+1];
        o.z = o2 + b2[4*l+2]; o.w = o3 + b2[4*l+3];
        *(float4*)(hf + (size_t)node * 16 + 4 * l) = o;
    }
}

// ---------------- Pooling + FC ----------------

__global__ __launch_bounds__(256) void pool_kernel(
    const float* __restrict__ hf, const int* __restrict__ batch,
    float* __restrict__ sums, float* __restrict__ counts, int n)
{
    int t = threadIdx.x;
    int d = t & 15, j = t >> 4;
    int base = blockIdx.x * 256 + j * 16;
    float run = 0.f, cnt = 0.f;
    int cg = -1;
    for (int i = 0; i < 16; ++i) {
        int nn = base + i;
        if (nn >= n) break;
        int g = batch[nn];
        if (g != cg) {
            if (cg >= 0) { atomicAdd(&sums[cg * 16 + d], run); if (d == 0) atomicAdd(&counts[cg], cnt); }
            cg = g; run = 0.f; cnt = 0.f;
        }
        run += hf[(size_t)nn * 16 + d];
        cnt += 1.f;
    }
    if (cg >= 0) { atomicAdd(&sums[cg * 16 + d], run); if (d == 0) atomicAdd(&counts[cg], cnt); }
}

__global__ void final_kernel(const float* __restrict__ sums, const float* __restrict__ counts,
                             const float* __restrict__ fcW, const float* __restrict__ fcb,
                             float* __restrict__ out, int G)
{
    int g = blockIdx.x * 64 + threadIdx.x;
    if (g < G) {
        float c = fmaxf(counts[g], 1.f);
        float s = 0.f;
        for (int dd = 0; dd < 16; ++dd) s += (sums[g * 16 + dd] / c) * fcW[dd];
        out[g] = s + fcb[0];
    }
}

// ---------------- launch ----------------

extern "C" void kernel_launch(void* const* d_in, const int* in_sizes, int n_in,
                              void* d_out, int out_size, void* d_ws, size_t ws_size,
                              hipStream_t stream)
{
    const float* x      = (const float*)d_in[0];
    const int*   ei     = (const int*)d_in[1];
    const int*   batch  = (const int*)d_in[2];
    const float* W1     = (const float*)d_in[3];
    const float* a_src1 = (const float*)d_in[4];
    const float* a_dst1 = (const float*)d_in[5];
    const float* b1     = (const float*)d_in[6];
    const float* W2     = (const float*)d_in[7];
    const float* a_src2 = (const float*)d_in[8];
    const float* a_dst2 = (const float*)d_in[9];
    const float* b2     = (const float*)d_in[10];
    const float* fcW    = (const float*)d_in[11];
    const float* fcb    = (const float*)d_in[12];
    float* out = (float*)d_out;

    int n = in_sizes[0] / 128;
    int E = in_sizes[1] / 2;
    int G = out_size;
    const int* srcA = ei;
    const int* dstA = ei + E;

    int nb = (n + (1 << CSR_SHIFT) - 1) >> CSR_SHIFT;
    int chunk = (E + CSR_NBLK - 1) / CSR_NBLK;

    char* p = (char*)d_ws;
    auto alloc = [&](size_t bytes) { char* r = p; p += (bytes + 255) & ~(size_t)255; return r; };
    int*   blockCntT  = (int*)alloc((size_t)nb * CSR_NBLK * 4);
    int*   tot        = (int*)alloc((size_t)nb * 4);
    int*   bucketBase = (int*)alloc((size_t)(nb + 1) * 4);
    int*   rowptr     = (int*)alloc((size_t)(n + 1) * 4);
    int*   csr        = (int*)alloc((size_t)E * 4);
    uint*  h1q        = (uint*)alloc((size_t)n * 32 * 4);    // fp8 x4 per uint
    float* as1        = (float*)alloc((size_t)n * 16);
    float* ad1        = (float*)alloc((size_t)n * 16);
    uint*  hrelu      = (uint*)alloc((size_t)n * 64 * 4);    // bf16 x2 per uint (128 dims)
    uint*  h2q        = (uint*)alloc((size_t)n * 16 * 4);    // bf16 x2 per uint
    float* as2        = (float*)alloc((size_t)n * 8);
    float* ad2        = (float*)alloc((size_t)n * 8);
    float* hf         = (float*)alloc((size_t)n * 16 * 4);
    float* sums       = (float*)alloc((size_t)(G * 16 + G + 1) * 4);
    float* counts     = sums + G * 16;
    int*   done       = (int*)(counts + G);

    // edge staging buffer aliases hrelu (E*4 = 6.6MB <= n*64*4 = 12.8MB);
    // fully consumed by local_csr_kernel before agg1 writes hrelu.
    uint* ebuf = (uint*)hrelu;

    hipMemsetAsync(sums, 0, (size_t)(G * 16 + G + 1) * 4, stream);

    bucket_count_kernel<<<CSR_NBLK, 256, 0, stream>>>(dstA, E, chunk, nb, blockCntT);
    row_scan_kernel<<<nb, 512, 0, stream>>>(blockCntT, tot, bucketBase, nb, done);
    bucket_scatter_kernel<<<CSR_NBLK, 256, 0, stream>>>(srcA, dstA, E, chunk, nb,
                                                        blockCntT, bucketBase, ebuf);
    local_csr_kernel<<<nb, 256, 0, stream>>>(ebuf, bucketBase, n, E, rowptr, csr);

    int gb = (n + 127) / 128;
    gemm_alpha_kernel<128, 4, false><<<gb, 256, 0, stream>>>(x, W1, a_src1, a_dst1,
                                                             h1q, as1, ad1, n);
    agg1_kernel<<<(n + 3) / 4, 256, 0, stream>>>(as1, ad1, h1q, rowptr, csr, b1, hrelu, n);
    gemm_alpha_kernel<32, 2, true><<<gb, 256, 0, stream>>>(hrelu, W2, a_src2, a_dst2,
                                                           h2q, as2, ad2, n);
    agg2_kernel<<<(n + 3) / 4, 256, 0, stream>>>(as2, ad2, h2q, rowptr, csr, b2, hf, n);
    pool_kernel<<<(n + 255) / 256, 256, 0, stream>>>(hf, batch, sums, counts, n);
    final_kernel<<<1, 64, 0, stream>>>(sums, counts, fcW, fcb, out, G);
}

// Round 11
// 205.738 us; speedup vs baseline: 1.2389x; 1.2389x over previous
//
#include <hip/hip_runtime.h>

#define LRELU(x) ((x) > 0.f ? (x) : 0.2f*(x))
typedef unsigned int uint;
typedef unsigned short ushort;

__device__ inline ushort f2bf(float f) {
    union { float f; unsigned u; } v; v.f = f;
    unsigned r = v.u + 0x7FFF + ((v.u >> 16) & 1);
    return (ushort)(r >> 16);
}
__device__ inline uint packbf(float a, float b) {
    return (uint)f2bf(a) | ((uint)f2bf(b) << 16);
}
__device__ inline float bflo(uint u){ union{uint u; float f;}v; v.u = u<<16; return v.f; }
__device__ inline float bfhi(uint u){ union{uint u; float f;}v; v.u = u & 0xFFFF0000u; return v.f; }

// ---------------- CSR build: atomic-free two-level bucket sort ----------------
// ebuf entries packed: (src << 7) | (dst & 127)
// NOTE: scan kept as TWO kernels deliberately — a fused last-block version
// needs agent-scope __threadfence(), which on multi-XCD gfx950 compiles to
// L2 writeback/invalidate and cost ~60us (measured R10). Kernel boundary
// gives the same ordering for ~4us.

#define CSR_SHIFT 7
#define CSR_NBLK  512

__global__ __launch_bounds__(256) void bucket_count_kernel(
    const int* __restrict__ dst, int E, int chunk, int nb,
    int* __restrict__ blockCntT)
{
    __shared__ int cnt[1024];
    int t = threadIdx.x, k = blockIdx.x;
    for (int i = t; i < nb; i += 256) cnt[i] = 0;
    __syncthreads();
    int e0 = k * chunk, e1 = min(e0 + chunk, E);
    for (int e = e0 + t; e < e1; e += 256)
        atomicAdd(&cnt[dst[e] >> CSR_SHIFT], 1);
    __syncthreads();
    for (int b = t; b < nb; b += 256)
        blockCntT[b * CSR_NBLK + k] = cnt[b];
}

__global__ __launch_bounds__(512) void row_scan_kernel(
    int* __restrict__ blockCntT, int* __restrict__ tot)
{
    __shared__ int sm[512];
    int b = blockIdx.x, t = threadIdx.x;
    int* row = blockCntT + b * CSR_NBLK;
    int v = row[t];
    sm[t] = v;
    __syncthreads();
    for (int off = 1; off < 512; off <<= 1) {
        int u = (t >= off) ? sm[t - off] : 0;
        __syncthreads(); sm[t] += u; __syncthreads();
    }
    row[t] = sm[t] - v;            // exclusive within bucket
    if (t == 511) tot[b] = sm[511];
}

__global__ __launch_bounds__(1024) void total_scan_kernel(
    const int* __restrict__ tot, int nb, int* __restrict__ bucketBase)
{
    __shared__ int sm[1024];
    int t = threadIdx.x;
    int v = (t < nb) ? tot[t] : 0;
    sm[t] = v;
    __syncthreads();
    for (int off = 1; off < 1024; off <<= 1) {
        int u = (t >= off) ? sm[t - off] : 0;
        __syncthreads(); sm[t] += u; __syncthreads();
    }
    if (t < nb) bucketBase[t] = sm[t] - v;
    if (t == 1023) bucketBase[nb] = sm[1023];
}

__global__ __launch_bounds__(256) void bucket_scatter_kernel(
    const int* __restrict__ src, const int* __restrict__ dst, int E, int chunk, int nb,
    const int* __restrict__ blockCntT, const int* __restrict__ bucketBase,
    uint* __restrict__ ebuf)
{
    __shared__ int cur[1024];
    int t = threadIdx.x, k = blockIdx.x;
    for (int b = t; b < nb; b += 256)
        cur[b] = bucketBase[b] + blockCntT[b * CSR_NBLK + k];
    __syncthreads();
    int e0 = k * chunk, e1 = min(e0 + chunk, E);
    for (int e = e0 + t; e < e1; e += 256) {
        int d = dst[e], s_ = src[e];
        int pos = atomicAdd(&cur[d >> CSR_SHIFT], 1);
        ebuf[pos] = ((uint)s_ << 7) | (uint)(d & 127);
    }
}

__global__ __launch_bounds__(256) void local_csr_kernel(
    const uint* __restrict__ ebuf, const int* __restrict__ bucketBase,
    int n, int E, int* __restrict__ rowptr, int* __restrict__ csr)
{
    __shared__ int lbase[1 << CSR_SHIFT];
    __shared__ int lcur[1 << CSR_SHIFT];
    __shared__ int ldeg[1 << CSR_SHIFT];
    int b = blockIdx.x, t = threadIdx.x;
    int n0 = b << CSR_SHIFT;
    int base = bucketBase[b], end = bucketBase[b + 1];
    if (t < (1 << CSR_SHIFT)) ldeg[t] = 0;
    __syncthreads();
    for (int e = base + t; e < end; e += 256)
        atomicAdd(&ldeg[ebuf[e] & 127], 1);
    __syncthreads();
    if (t == 0) {
        int run = base;
        for (int i = 0; i < (1 << CSR_SHIFT); ++i) {
            lbase[i] = run; lcur[i] = run; run += ldeg[i];
        }
    }
    __syncthreads();
    int node = n0 + t;
    if (t < (1 << CSR_SHIFT) && node < n) rowptr[node] = lbase[t];
    if (b == 0 && t == 0) rowptr[n] = E;
    for (int e = base + t; e < end; e += 256) {
        uint ed = ebuf[e];
        int pos = atomicAdd(&lcur[ed & 127], 1);
        csr[pos] = (int)(ed >> 7);
    }
}

// ---------------- GEMM + fused alpha dots ----------------
// NPT=4 nodes/thread. XBF16: input rows are bf16 (packed u32 pairs).
// COLS=128 -> fp8 e4m3 output; COLS=32 -> bf16 output.

template<int COLS, int HEADS, bool XBF16>
__global__ __launch_bounds__(256) void gemm_alpha_kernel(
    const void* __restrict__ xin, const float* __restrict__ W,
    const float* __restrict__ a_src, const float* __restrict__ a_dst,
    uint* __restrict__ hq, float* __restrict__ as_out,
    float* __restrict__ ad_out, int n)
{
    constexpr int K = 128;
    constexpr int CPT = COLS / 8;
    constexpr int NPT = 4;
    constexpr int DIM = COLS / HEADS;
    constexpr int TPH = DIM / CPT;
    constexpr int NSLOT = COLS / 4;
    __shared__ float4 WL[K * NSLOT];

    int t = threadIdx.x;
    for (int idx = t * 4; idx < K * COLS; idx += 1024) {
        float4 w = *(const float4*)(W + idx);
        int k = idx / COLS, c = idx % COLS;
        int slot = c >> 2;
        if (COLS == 128) slot = (slot >> 2) | ((slot & 3) << 3);
        WL[k * NSLOT + slot] = w;
    }
    __syncthreads();

    int m_ = t & 7;
    int node0 = blockIdx.x * (32 * NPT) + (t >> 3) * NPT;
    if (node0 >= n) return;
    int c0 = m_ * CPT;

    size_t rows[NPT];
#pragma unroll
    for (int i = 0; i < NPT; i++) rows[i] = (size_t)min(node0 + i, n - 1);

    float acc[NPT][CPT];
#pragma unroll
    for (int i = 0; i < NPT; i++)
#pragma unroll
        for (int q = 0; q < CPT; q++) acc[i][q] = 0.f;

    for (int k4 = 0; k4 < K; k4 += 4) {
        float xs[NPT][4];
#pragma unroll
        for (int i = 0; i < NPT; i++) {
            if constexpr (XBF16) {
                uint2 u = *(const uint2*)((const uint*)xin + rows[i] * 64 + (k4 >> 1));
                xs[i][0] = bflo(u.x); xs[i][1] = bfhi(u.x);
                xs[i][2] = bflo(u.y); xs[i][3] = bfhi(u.y);
            } else {
                float4 v = *(const float4*)((const float*)xin + rows[i] * 128 + k4);
                xs[i][0] = v.x; xs[i][1] = v.y; xs[i][2] = v.z; xs[i][3] = v.w;
            }
        }
#pragma unroll
        for (int kk = 0; kk < 4; kk++) {
#pragma unroll
            for (int j = 0; j < CPT / 4; j++) {
                int slot = (COLS == 128) ? (m_ | (j << 3)) : m_;
                float4 w = WL[(k4 + kk) * NSLOT + slot];
#pragma unroll
                for (int i = 0; i < NPT; i++) {
                    float xa = xs[i][kk];
                    acc[i][j*4+0] += xa * w.x;
                    acc[i][j*4+1] += xa * w.y;
                    acc[i][j*4+2] += xa * w.z;
                    acc[i][j*4+3] += xa * w.w;
                }
            }
        }
    }

    int head = c0 / DIM, lc = c0 - head * DIM;
    float asc[CPT], adc[CPT];
#pragma unroll
    for (int q = 0; q < CPT; q++) {
        asc[q] = a_src[head * DIM + lc + q];
        adc[q] = a_dst[head * DIM + lc + q];
    }

#pragma unroll
    for (int i = 0; i < NPT; i++) {
        int node = node0 + i;
        if (node >= n) break;
        if constexpr (COLS == 128) {
            uint wds[4];
#pragma unroll
            for (int j = 0; j < 4; j++) {
                int u = 0;
                u = __builtin_amdgcn_cvt_pk_fp8_f32(acc[i][j*4+0], acc[i][j*4+1], u, false);
                u = __builtin_amdgcn_cvt_pk_fp8_f32(acc[i][j*4+2], acc[i][j*4+3], u, true);
                wds[j] = (uint)u;
            }
            *(uint4*)(hq + (size_t)node * 32 + m_ * 4) = make_uint4(wds[0], wds[1], wds[2], wds[3]);
        } else {
            uint w0 = packbf(acc[i][0], acc[i][1]);
            uint w1 = packbf(acc[i][2], acc[i][3]);
            *(uint2*)(hq + (size_t)node * 16 + m_ * 2) = make_uint2(w0, w1);
        }
        float ps = 0.f, pd = 0.f;
#pragma unroll
        for (int q = 0; q < CPT; q++) {
            ps += acc[i][q] * asc[q];
            pd += acc[i][q] * adc[q];
        }
#pragma unroll
        for (int off = 1; off < TPH; off <<= 1) {
            ps += __shfl_xor(ps, off);
            pd += __shfl_xor(pd, off);
        }
        if ((m_ & (TPH - 1)) == 0) {
            as_out[node * HEADS + head] = ps;
            ad_out[node * HEADS + head] = pd;
        }
    }
}

// ---------------- Layer-1 aggregation (flat, fp8 gather) ----------------
// One wave per node; no LDS/barriers. 8 groups x 8 lanes; group g owns edges
// rp+g+8k. Lane: head=l>>1, dims 16l..16l+15 (uint4 = 16 fp8). Non-temporal
// csr stream read preserves L2 for the h1q table. Output hrelu in bf16.

__global__ __launch_bounds__(256) void agg1_kernel(
    const float* __restrict__ as1f, const float* __restrict__ ad1f,
    const uint* __restrict__ h1q, const int* __restrict__ rowptr,
    const int* __restrict__ csr, const float* __restrict__ b1,
    uint* __restrict__ hrelu, int n)
{
    int t = threadIdx.x;
    int w = t >> 6, tw = t & 63;
    int g = tw >> 3, l = tw & 7;   // 8 groups x 8 lanes
    int head = l >> 1;
    int node = blockIdx.x * 4 + w;
    if (node >= n) return;

    float adh = ad1f[node * 4 + head];
    int rp = rowptr[node], re = rowptr[node + 1];

    float acc[16];
#pragma unroll
    for (int i = 0; i < 16; i++) acc[i] = 0.f;
    float den = 0.f;

#pragma unroll 2
    for (int e = rp + g; e < re; e += 8) {
        int s = __builtin_nontemporal_load(csr + e);
        float a = as1f[s * 4 + head];
        uint4 u = *(const uint4*)(h1q + ((size_t)s << 5) + (l << 2));
        float ex = __expf(LRELU(a + adh));
        den += ex;
        uint ua[4] = {u.x, u.y, u.z, u.w};
#pragma unroll
        for (int j = 0; j < 4; j++) {
            auto p0 = __builtin_amdgcn_cvt_pk_f32_fp8(ua[j], false);
            auto p1 = __builtin_amdgcn_cvt_pk_f32_fp8(ua[j], true);
            acc[j*4+0] += ex * p0[0]; acc[j*4+1] += ex * p0[1];
            acc[j*4+2] += ex * p1[0]; acc[j*4+3] += ex * p1[1];
        }
    }

    if (g == 0) {   // self loop, counted once (pre-reduction)
        float a = as1f[node * 4 + head];
        float ex = __expf(LRELU(a + adh));
        den += ex;
        uint4 u = *(const uint4*)(h1q + ((size_t)node << 5) + (l << 2));
        uint ua[4] = {u.x, u.y, u.z, u.w};
#pragma unroll
        for (int j = 0; j < 4; j++) {
            auto p0 = __builtin_amdgcn_cvt_pk_f32_fp8(ua[j], false);
            auto p1 = __builtin_amdgcn_cvt_pk_f32_fp8(ua[j], true);
            acc[j*4+0] += ex * p0[0]; acc[j*4+1] += ex * p0[1];
            acc[j*4+2] += ex * p1[0]; acc[j*4+3] += ex * p1[1];
        }
    }

    // reduce across the 8 groups (lane-id bits 3,4,5)
#pragma unroll
    for (int i = 0; i < 16; i++) {
        acc[i] += __shfl_xor(acc[i], 8);
        acc[i] += __shfl_xor(acc[i], 16);
        acc[i] += __shfl_xor(acc[i], 32);
    }
    den += __shfl_xor(den, 8);
    den += __shfl_xor(den, 16);
    den += __shfl_xor(den, 32);

    if (g == 0) {
        float inv = 1.f / (den + 1e-16f);
        uint o[8];
#pragma unroll
        for (int j = 0; j < 4; j++) {
            float v0 = fmaxf(acc[j*4+0] * inv + b1[16*l + 4*j + 0], 0.f);
            float v1 = fmaxf(acc[j*4+1] * inv + b1[16*l + 4*j + 1], 0.f);
            float v2 = fmaxf(acc[j*4+2] * inv + b1[16*l + 4*j + 2], 0.f);
            float v3 = fmaxf(acc[j*4+3] * inv + b1[16*l + 4*j + 3], 0.f);
            o[2*j]   = packbf(v0, v1);
            o[2*j+1] = packbf(v2, v3);
        }
        uint* hp = hrelu + (size_t)node * 64 + l * 8;
        *(uint4*)hp       = make_uint4(o[0], o[1], o[2], o[3]);
        *(uint4*)(hp + 4) = make_uint4(o[4], o[5], o[6], o[7]);
    }
}

// ---------------- Layer-2 aggregation (flat, bf16 gather, head-mean) ----------

__global__ __launch_bounds__(256) void agg2_kernel(
    const float* __restrict__ as2f, const float* __restrict__ ad2f,
    const uint* __restrict__ h2q, const int* __restrict__ rowptr,
    const int* __restrict__ csr, const float* __restrict__ b2,
    float* __restrict__ hf, int n)
{
    int t = threadIdx.x;
    int w = t >> 6, tw = t & 63;
    int g = tw >> 3, l = tw & 7;
    int head = l >> 2;
    int node = blockIdx.x * 4 + w;
    if (node >= n) return;

    float adh = ad2f[node * 2 + head];
    int rp = rowptr[node], re = rowptr[node + 1];

    float acc[4] = {0.f, 0.f, 0.f, 0.f};
    float den = 0.f;

#pragma unroll 2
    for (int e = rp + g; e < re; e += 8) {
        int s = __builtin_nontemporal_load(csr + e);
        float a = as2f[s * 2 + head];
        uint2 u = *(const uint2*)(h2q + ((size_t)s << 4) + (l << 1));
        float ex = __expf(LRELU(a + adh));
        den += ex;
        acc[0] += ex * bflo(u.x); acc[1] += ex * bfhi(u.x);
        acc[2] += ex * bflo(u.y); acc[3] += ex * bfhi(u.y);
    }

    if (g == 0) {   // self loop
        float a = as2f[node * 2 + head];
        float ex = __expf(LRELU(a + adh));
        den += ex;
        uint2 u = *(const uint2*)(h2q + ((size_t)node << 4) + (l << 1));
        acc[0] += ex * bflo(u.x); acc[1] += ex * bfhi(u.x);
        acc[2] += ex * bflo(u.y); acc[3] += ex * bfhi(u.y);
    }

#pragma unroll
    for (int i = 0; i < 4; i++) {
        acc[i] += __shfl_xor(acc[i], 8);
        acc[i] += __shfl_xor(acc[i], 16);
        acc[i] += __shfl_xor(acc[i], 32);
    }
    den += __shfl_xor(den, 8);
    den += __shfl_xor(den, 16);
    den += __shfl_xor(den, 32);

    float inv = 1.f / (den + 1e-16f);
    float v0 = acc[0] * inv, v1 = acc[1] * inv, v2 = acc[2] * inv, v3 = acc[3] * inv;
    // mean over heads: lane l (head0, dims 4l..) pairs with lane l^4 (head1)
    float o0 = 0.5f * (v0 + __shfl_xor(v0, 4));
    float o1 = 0.5f * (v1 + __shfl_xor(v1, 4));
    float o2 = 0.5f * (v2 + __shfl_xor(v2, 4));
    float o3 = 0.5f * (v3 + __shfl_xor(v3, 4));
    if (g == 0 && l < 4) {
        float4 o;
        o.x = o0 + b2[4*l+0]; o.y = o1 + b2[4*l+1];
        o.z = o2 + b2[4*l+2]; o.w = o3 + b2[4*l+3];
        *(float4*)(hf + (size_t)node * 16 + 4 * l) = o;
    }
}

// ---------------- Pooling + FC ----------------

__global__ __launch_bounds__(256) void pool_kernel(
    const float* __restrict__ hf, const int* __restrict__ batch,
    float* __restrict__ sums, float* __restrict__ counts, int n)
{
    int t = threadIdx.x;
    int d = t & 15, j = t >> 4;
    int base = blockIdx.x * 256 + j * 16;
    float run = 0.f, cnt = 0.f;
    int cg = -1;
    for (int i = 0; i < 16; ++i) {
        int nn = base + i;
        if (nn >= n) break;
        int g = batch[nn];
        if (g != cg) {
            if (cg >= 0) { atomicAdd(&sums[cg * 16 + d], run); if (d == 0) atomicAdd(&counts[cg], cnt); }
            cg = g; run = 0.f; cnt = 0.f;
        }
        run += hf[(size_t)nn * 16 + d];
        cnt += 1.f;
    }
    if (cg >= 0) { atomicAdd(&sums[cg * 16 + d], run); if (d == 0) atomicAdd(&counts[cg], cnt); }
}

__global__ void final_kernel(const float* __restrict__ sums, const float* __restrict__ counts,
                             const float* __restrict__ fcW, const float* __restrict__ fcb,
                             float* __restrict__ out, int G)
{
    int g = blockIdx.x * 64 + threadIdx.x;
    if (g < G) {
        float c = fmaxf(counts[g], 1.f);
        float s = 0.f;
        for (int dd = 0; dd < 16; ++dd) s += (sums[g * 16 + dd] / c) * fcW[dd];
        out[g] = s + fcb[0];
    }
}

// ---------------- launch ----------------

extern "C" void kernel_launch(void* const* d_in, const int* in_sizes, int n_in,
                              void* d_out, int out_size, void* d_ws, size_t ws_size,
                              hipStream_t stream)
{
    const float* x      = (const float*)d_in[0];
    const int*   ei     = (const int*)d_in[1];
    const int*   batch  = (const int*)d_in[2];
    const float* W1     = (const float*)d_in[3];
    const float* a_src1 = (const float*)d_in[4];
    const float* a_dst1 = (const float*)d_in[5];
    const float* b1     = (const float*)d_in[6];
    const float* W2     = (const float*)d_in[7];
    const float* a_src2 = (const float*)d_in[8];
    const float* a_dst2 = (const float*)d_in[9];
    const float* b2     = (const float*)d_in[10];
    const float* fcW    = (const float*)d_in[11];
    const float* fcb    = (const float*)d_in[12];
    float* out = (float*)d_out;

    int n = in_sizes[0] / 128;
    int E = in_sizes[1] / 2;
    int G = out_size;
    const int* srcA = ei;
    const int* dstA = ei + E;

    int nb = (n + (1 << CSR_SHIFT) - 1) >> CSR_SHIFT;
    int chunk = (E + CSR_NBLK - 1) / CSR_NBLK;

    char* p = (char*)d_ws;
    auto alloc = [&](size_t bytes) { char* r = p; p += (bytes + 255) & ~(size_t)255; return r; };
    int*   blockCntT  = (int*)alloc((size_t)nb * CSR_NBLK * 4);
    int*   tot        = (int*)alloc((size_t)nb * 4);
    int*   bucketBase = (int*)alloc((size_t)(nb + 1) * 4);
    int*   rowptr     = (int*)alloc((size_t)(n + 1) * 4);
    int*   csr        = (int*)alloc((size_t)E * 4);
    uint*  h1q        = (uint*)alloc((size_t)n * 32 * 4);    // fp8 x4 per uint
    float* as1        = (float*)alloc((size_t)n * 16);
    float* ad1        = (float*)alloc((size_t)n * 16);
    uint*  hrelu      = (uint*)alloc((size_t)n * 64 * 4);    // bf16 x2 per uint (128 dims)
    uint*  h2q        = (uint*)alloc((size_t)n * 16 * 4);    // bf16 x2 per uint
    float* as2        = (float*)alloc((size_t)n * 8);
    float* ad2        = (float*)alloc((size_t)n * 8);
    float* hf         = (float*)alloc((size_t)n * 16 * 4);
    float* sums       = (float*)alloc((size_t)(G * 16 + G) * 4);
    float* counts     = sums + G * 16;

    // edge staging buffer aliases hrelu (E*4 = 6.6MB <= n*64*4 = 12.8MB);
    // fully consumed by local_csr_kernel before agg1 writes hrelu.
    uint* ebuf = (uint*)hrelu;

    hipMemsetAsync(sums, 0, (size_t)(G * 16 + G) * 4, stream);

    bucket_count_kernel<<<CSR_NBLK, 256, 0, stream>>>(dstA, E, chunk, nb, blockCntT);
    row_scan_kernel<<<nb, 512, 0, stream>>>(blockCntT, tot);
    total_scan_kernel<<<1, 1024, 0, stream>>>(tot, nb, bucketBase);
    bucket_scatter_kernel<<<CSR_NBLK, 256, 0, stream>>>(srcA, dstA, E, chunk, nb,
                                                        blockCntT, bucketBase, ebuf);
    local_csr_kernel<<<nb, 256, 0, stream>>>(ebuf, bucketBase, n, E, rowptr, csr);

    int gb = (n + 127) / 128;
    gemm_alpha_kernel<128, 4, false><<<gb, 256, 0, stream>>>(x, W1, a_src1, a_dst1,
                                                             h1q, as1, ad1, n);
    agg1_kernel<<<(n + 3) / 4, 256, 0, stream>>>(as1, ad1, h1q, rowptr, csr, b1, hrelu, n);
    gemm_alpha_kernel<32, 2, true><<<gb, 256, 0, stream>>>(hrelu, W2, a_src2, a_dst2,
                                                           h2q, as2, ad2, n);
    agg2_kernel<<<(n + 3) / 4, 256, 0, stream>>>(as2, ad2, h2q, rowptr, csr, b2, hf, n);
    pool_kernel<<<(n + 255) / 256, 256, 0, stream>>>(hf, batch, sums, counts, n);
    final_kernel<<<1, 64, 0, stream>>>(sums, counts, fcW, fcb, out, G);
}

// Round 13
// 201.753 us; speedup vs baseline: 1.2634x; 1.0198x over previous
//
#include <hip/hip_runtime.h>

#define LRELU(x) ((x) > 0.f ? (x) : 0.2f*(x))
typedef unsigned int uint;
typedef unsigned short ushort;
typedef _Float16 half2_t __attribute__((ext_vector_type(2)));

__device__ inline ushort f2bf(float f) {
    union { float f; unsigned u; } v; v.f = f;
    unsigned r = v.u + 0x7FFF + ((v.u >> 16) & 1);
    return (ushort)(r >> 16);
}
__device__ inline uint packbf(float a, float b) {
    return (uint)f2bf(a) | ((uint)f2bf(b) << 16);
}
__device__ inline float bflo(uint u){ union{uint u; float f;}v; v.u = u<<16; return v.f; }
__device__ inline float bfhi(uint u){ union{uint u; float f;}v; v.u = u & 0xFFFF0000u; return v.f; }
__device__ inline half2_t u2h(uint u){ union{uint u; half2_t h;}v; v.u=u; return v.h; }
__device__ inline uint h2u(half2_t h){ union{half2_t h; uint u;}v; v.h=h; return v.u; }
__device__ inline uint packh(float a, float b){
    half2_t h; h.x = (_Float16)a; h.y = (_Float16)b; return h2u(h);
}

// ---------------- CSR build: atomic-free two-level bucket sort ----------------
// ebuf entries packed: (src << 7) | (dst & 127)
// Scan kept as TWO kernels deliberately — fused last-block version needs
// agent-scope __threadfence() = L2 writeback on multi-XCD gfx950 (~60us, R10).

#define CSR_SHIFT 7
#define CSR_NBLK  512

__global__ __launch_bounds__(256) void bucket_count_kernel(
    const int* __restrict__ dst, int E, int chunk, int nb,
    int* __restrict__ blockCntT)
{
    __shared__ int cnt[1024];
    int t = threadIdx.x, k = blockIdx.x;
    for (int i = t; i < nb; i += 256) cnt[i] = 0;
    __syncthreads();
    int e0 = k * chunk, e1 = min(e0 + chunk, E);
    for (int e = e0 + t; e < e1; e += 256)
        atomicAdd(&cnt[dst[e] >> CSR_SHIFT], 1);
    __syncthreads();
    for (int b = t; b < nb; b += 256)
        blockCntT[b * CSR_NBLK + k] = cnt[b];
}

__global__ __launch_bounds__(512) void row_scan_kernel(
    int* __restrict__ blockCntT, int* __restrict__ tot)
{
    __shared__ int sm[512];
    int b = blockIdx.x, t = threadIdx.x;
    int* row = blockCntT + b * CSR_NBLK;
    int v = row[t];
    sm[t] = v;
    __syncthreads();
    for (int off = 1; off < 512; off <<= 1) {
        int u = (t >= off) ? sm[t - off] : 0;
        __syncthreads(); sm[t] += u; __syncthreads();
    }
    row[t] = sm[t] - v;            // exclusive within bucket
    if (t == 511) tot[b] = sm[511];
}

__global__ __launch_bounds__(1024) void total_scan_kernel(
    const int* __restrict__ tot, int nb, int* __restrict__ bucketBase)
{
    __shared__ int sm[1024];
    int t = threadIdx.x;
    int v = (t < nb) ? tot[t] : 0;
    sm[t] = v;
    __syncthreads();
    for (int off = 1; off < 1024; off <<= 1) {
        int u = (t >= off) ? sm[t - off] : 0;
        __syncthreads(); sm[t] += u; __syncthreads();
    }
    if (t < nb) bucketBase[t] = sm[t] - v;
    if (t == 1023) bucketBase[nb] = sm[1023];
}

__global__ __launch_bounds__(256) void bucket_scatter_kernel(
    const int* __restrict__ src, const int* __restrict__ dst, int E, int chunk, int nb,
    const int* __restrict__ blockCntT, const int* __restrict__ bucketBase,
    uint* __restrict__ ebuf)
{
    __shared__ int cur[1024];
    int t = threadIdx.x, k = blockIdx.x;
    for (int b = t; b < nb; b += 256)
        cur[b] = bucketBase[b] + blockCntT[b * CSR_NBLK + k];
    __syncthreads();
    int e0 = k * chunk, e1 = min(e0 + chunk, E);
    for (int e = e0 + t; e < e1; e += 256) {
        int d = dst[e], s_ = src[e];
        int pos = atomicAdd(&cur[d >> CSR_SHIFT], 1);
        ebuf[pos] = ((uint)s_ << 7) | (uint)(d & 127);
    }
}

__global__ __launch_bounds__(256) void local_csr_kernel(
    const uint* __restrict__ ebuf, const int* __restrict__ bucketBase,
    int n, int E, int* __restrict__ rowptr, int* __restrict__ csr)
{
    __shared__ int lbase[1 << CSR_SHIFT];
    __shared__ int lcur[1 << CSR_SHIFT];
    __shared__ int ldeg[1 << CSR_SHIFT];
    int b = blockIdx.x, t = threadIdx.x;
    int n0 = b << CSR_SHIFT;
    int base = bucketBase[b], end = bucketBase[b + 1];
    if (t < (1 << CSR_SHIFT)) ldeg[t] = 0;
    __syncthreads();
    for (int e = base + t; e < end; e += 256)
        atomicAdd(&ldeg[ebuf[e] & 127], 1);
    __syncthreads();
    if (t == 0) {
        int run = base;
        for (int i = 0; i < (1 << CSR_SHIFT); ++i) {
            lbase[i] = run; lcur[i] = run; run += ldeg[i];
        }
    }
    __syncthreads();
    int node = n0 + t;
    if (t < (1 << CSR_SHIFT) && node < n) rowptr[node] = lbase[t];
    if (b == 0 && t == 0) rowptr[n] = E;
    for (int e = base + t; e < end; e += 256) {
        uint ed = ebuf[e];
        int pos = atomicAdd(&lcur[ed & 127], 1);
        csr[pos] = (int)(ed >> 7);
    }
}

// ---------------- GEMM + fused alpha dots (f16 dot2 inner loop) ----------------
// W staged in LDS as f16 K-PAIRS: WLH[k2][c] = pack(W[2k2][c], W[2k2+1][c]).
// LDS = K/2*COLS*4B (32KB for COLS=128 vs 64KB fp32 -> 2x occupancy), and
// v_dot2_f32_f16 does 2 MACs/instr. x converted to f16 pairs in-loop.
// NPT=4 nodes/thread. COLS=128 -> fp8 e4m3 output; COLS=32 -> bf16 output.

template<int COLS, int HEADS>
__global__ __launch_bounds__(256) void gemm_alpha_kernel(
    const float* __restrict__ x, const float* __restrict__ W,
    const float* __restrict__ a_src, const float* __restrict__ a_dst,
    uint* __restrict__ hq, float* __restrict__ as_out,
    float* __restrict__ ad_out, int n)
{
    constexpr int K = 128;
    constexpr int K2 = K / 2;
    constexpr int CPT = COLS / 8;       // cols per thread (16 or 4)
    constexpr int NPT = 4;
    constexpr int DIM = COLS / HEADS;
    constexpr int TPH = DIM / CPT;      // 2 or 4
    constexpr int NSLOT4 = COLS / 4;    // uint4 slots per k2-row
    __shared__ uint WLH[K2 * COLS];     // f16x2 per uint

    int t = threadIdx.x;
    for (int sid = t; sid < K2 * NSLOT4; sid += 256) {
        int k2 = sid / NSLOT4, c = (sid % NSLOT4) * 4;
        float4 w0 = *(const float4*)(W + (2 * k2) * COLS + c);
        float4 w1 = *(const float4*)(W + (2 * k2 + 1) * COLS + c);
        uint4 u;
        u.x = packh(w0.x, w1.x);
        u.y = packh(w0.y, w1.y);
        u.z = packh(w0.z, w1.z);
        u.w = packh(w0.w, w1.w);
        ((uint4*)WLH)[sid] = u;
    }
    __syncthreads();

    int m_ = t & 7;
    int node0 = blockIdx.x * (32 * NPT) + (t >> 3) * NPT;
    if (node0 >= n) return;
    int c0 = m_ * CPT;

    size_t rows[NPT];
#pragma unroll
    for (int i = 0; i < NPT; i++) rows[i] = (size_t)min(node0 + i, n - 1);

    float acc[NPT][CPT];
#pragma unroll
    for (int i = 0; i < NPT; i++)
#pragma unroll
        for (int q = 0; q < CPT; q++) acc[i][q] = 0.f;

    for (int k4 = 0; k4 < K; k4 += 4) {     // 4 k-values = 2 k2-pairs per iter
        half2_t xp[NPT][2];
#pragma unroll
        for (int i = 0; i < NPT; i++) {
            float4 v = *(const float4*)(x + rows[i] * K + k4);
            half2_t h0; h0.x = (_Float16)v.x; h0.y = (_Float16)v.y;
            half2_t h1; h1.x = (_Float16)v.z; h1.y = (_Float16)v.w;
            xp[i][0] = h0;
            xp[i][1] = h1;
        }
#pragma unroll
        for (int p = 0; p < 2; p++) {
            int k2 = (k4 >> 1) + p;
#pragma unroll
            for (int j = 0; j < CPT / 4; j++) {
                uint4 wq = ((const uint4*)WLH)[k2 * NSLOT4 + m_ * (CPT / 4) + j];
                half2_t w0 = u2h(wq.x), w1 = u2h(wq.y), w2 = u2h(wq.z), w3 = u2h(wq.w);
#pragma unroll
                for (int i = 0; i < NPT; i++) {
                    half2_t xv = xp[i][p];
                    acc[i][j*4+0] = __builtin_amdgcn_fdot2(xv, w0, acc[i][j*4+0], false);
                    acc[i][j*4+1] = __builtin_amdgcn_fdot2(xv, w1, acc[i][j*4+1], false);
                    acc[i][j*4+2] = __builtin_amdgcn_fdot2(xv, w2, acc[i][j*4+2], false);
                    acc[i][j*4+3] = __builtin_amdgcn_fdot2(xv, w3, acc[i][j*4+3], false);
                }
            }
        }
    }

    int head = c0 / DIM, lc = c0 - head * DIM;
    float asc[CPT], adc[CPT];
#pragma unroll
    for (int q = 0; q < CPT; q++) {
        asc[q] = a_src[head * DIM + lc + q];
        adc[q] = a_dst[head * DIM + lc + q];
    }

#pragma unroll
    for (int i = 0; i < NPT; i++) {
        int node = node0 + i;
        if (node >= n) break;
        if constexpr (COLS == 128) {
            uint wds[4];
#pragma unroll
            for (int j = 0; j < 4; j++) {
                int u = 0;
                u = __builtin_amdgcn_cvt_pk_fp8_f32(acc[i][j*4+0], acc[i][j*4+1], u, false);
                u = __builtin_amdgcn_cvt_pk_fp8_f32(acc[i][j*4+2], acc[i][j*4+3], u, true);
                wds[j] = (uint)u;
            }
            *(uint4*)(hq + (size_t)node * 32 + m_ * 4) = make_uint4(wds[0], wds[1], wds[2], wds[3]);
        } else {
            uint w0 = packbf(acc[i][0], acc[i][1]);
            uint w1 = packbf(acc[i][2], acc[i][3]);
            *(uint2*)(hq + (size_t)node * 16 + m_ * 2) = make_uint2(w0, w1);
        }
        float ps = 0.f, pd = 0.f;
#pragma unroll
        for (int q = 0; q < CPT; q++) {
            ps += acc[i][q] * asc[q];
            pd += acc[i][q] * adc[q];
        }
#pragma unroll
        for (int off = 1; off < TPH; off <<= 1) {
            ps += __shfl_xor(ps, off);
            pd += __shfl_xor(pd, off);
        }
        if ((m_ & (TPH - 1)) == 0) {
            as_out[node * HEADS + head] = ps;
            ad_out[node * HEADS + head] = pd;
        }
    }
}

// ---------------- Layer-1 aggregation (flat, fp8 gather — R8 best) ------------
// One wave per node; no LDS/barriers. 8 groups x 8 lanes; group g owns edges
// rp+g+8k. Lane: head=l>>1, dims 16l..16l+15 (uint4 = 16 fp8).

__global__ __launch_bounds__(256) void agg1_kernel(
    const float* __restrict__ as1f, const float* __restrict__ ad1f,
    const uint* __restrict__ h1q, const int* __restrict__ rowptr,
    const int* __restrict__ csr, const float* __restrict__ b1,
    float* __restrict__ hout, int n)
{
    int t = threadIdx.x;
    int w = t >> 6, tw = t & 63;
    int g = tw >> 3, l = tw & 7;   // 8 groups x 8 lanes
    int head = l >> 1;
    int node = blockIdx.x * 4 + w;
    if (node >= n) return;

    float adh = ad1f[node * 4 + head];
    int rp = rowptr[node], re = rowptr[node + 1];

    float acc[16];
#pragma unroll
    for (int i = 0; i < 16; i++) acc[i] = 0.f;
    float den = 0.f;

#pragma unroll 2
    for (int e = rp + g; e < re; e += 8) {
        int s = csr[e];
        float a = as1f[s * 4 + head];
        uint4 u = *(const uint4*)(h1q + ((size_t)s << 5) + (l << 2));
        float ex = __expf(LRELU(a + adh));
        den += ex;
        uint ua[4] = {u.x, u.y, u.z, u.w};
#pragma unroll
        for (int j = 0; j < 4; j++) {
            auto p0 = __builtin_amdgcn_cvt_pk_f32_fp8(ua[j], false);
            auto p1 = __builtin_amdgcn_cvt_pk_f32_fp8(ua[j], true);
            acc[j*4+0] += ex * p0[0]; acc[j*4+1] += ex * p0[1];
            acc[j*4+2] += ex * p1[0]; acc[j*4+3] += ex * p1[1];
        }
    }

    if (g == 0) {   // self loop, counted once (pre-reduction)
        float a = as1f[node * 4 + head];
        float ex = __expf(LRELU(a + adh));
        den += ex;
        uint4 u = *(const uint4*)(h1q + ((size_t)node << 5) + (l << 2));
        uint ua[4] = {u.x, u.y, u.z, u.w};
#pragma unroll
        for (int j = 0; j < 4; j++) {
            auto p0 = __builtin_amdgcn_cvt_pk_f32_fp8(ua[j], false);
            auto p1 = __builtin_amdgcn_cvt_pk_f32_fp8(ua[j], true);
            acc[j*4+0] += ex * p0[0]; acc[j*4+1] += ex * p0[1];
            acc[j*4+2] += ex * p1[0]; acc[j*4+3] += ex * p1[1];
        }
    }

    // reduce across the 8 groups (lane-id bits 3,4,5)
#pragma unroll
    for (int i = 0; i < 16; i++) {
        acc[i] += __shfl_xor(acc[i], 8);
        acc[i] += __shfl_xor(acc[i], 16);
        acc[i] += __shfl_xor(acc[i], 32);
    }
    den += __shfl_xor(den, 8);
    den += __shfl_xor(den, 16);
    den += __shfl_xor(den, 32);

    if (g == 0) {
        float inv = 1.f / (den + 1e-16f);
        const float4* b4 = (const float4*)b1;
#pragma unroll
        for (int j = 0; j < 4; j++) {
            float4 bv = b4[(l << 2) + j];
            float4 o;
            o.x = fmaxf(acc[j*4+0] * inv + bv.x, 0.f);
            o.y = fmaxf(acc[j*4+1] * inv + bv.y, 0.f);
            o.z = fmaxf(acc[j*4+2] * inv + bv.z, 0.f);
            o.w = fmaxf(acc[j*4+3] * inv + bv.w, 0.f);
            ((float4*)hout)[(size_t)node * 32 + (l << 2) + j] = o;
        }
    }
}

// ---------------- Layer-2 aggregation (flat, bf16 gather, head-mean — R8) -----

__global__ __launch_bounds__(256) void agg2_kernel(
    const float* __restrict__ as2f, const float* __restrict__ ad2f,
    const uint* __restrict__ h2q, const int* __restrict__ rowptr,
    const int* __restrict__ csr, const float* __restrict__ b2,
    float* __restrict__ hf, int n)
{
    int t = threadIdx.x;
    int w = t >> 6, tw = t & 63;
    int g = tw >> 3, l = tw & 7;
    int head = l >> 2;
    int node = blockIdx.x * 4 + w;
    if (node >= n) return;

    float adh = ad2f[node * 2 + head];
    int rp = rowptr[node], re = rowptr[node + 1];

    float acc[4] = {0.f, 0.f, 0.f, 0.f};
    float den = 0.f;

#pragma unroll 2
    for (int e = rp + g; e < re; e += 8) {
        int s = csr[e];
        float a = as2f[s * 2 + head];
        uint2 u = *(const uint2*)(h2q + ((size_t)s << 4) + (l << 1));
        float ex = __expf(LRELU(a + adh));
        den += ex;
        acc[0] += ex * bflo(u.x); acc[1] += ex * bfhi(u.x);
        acc[2] += ex * bflo(u.y); acc[3] += ex * bfhi(u.y);
    }

    if (g == 0) {   // self loop
        float a = as2f[node * 2 + head];
        float ex = __expf(LRELU(a + adh));
        den += ex;
        uint2 u = *(const uint2*)(h2q + ((size_t)node << 4) + (l << 1));
        acc[0] += ex * bflo(u.x); acc[1] += ex * bfhi(u.x);
        acc[2] += ex * bflo(u.y); acc[3] += ex * bfhi(u.y);
    }

#pragma unroll
    for (int i = 0; i < 4; i++) {
        acc[i] += __shfl_xor(acc[i], 8);
        acc[i] += __shfl_xor(acc[i], 16);
        acc[i] += __shfl_xor(acc[i], 32);
    }
    den += __shfl_xor(den, 8);
    den += __shfl_xor(den, 16);
    den += __shfl_xor(den, 32);

    float inv = 1.f / (den + 1e-16f);
    float v0 = acc[0] * inv, v1 = acc[1] * inv, v2 = acc[2] * inv, v3 = acc[3] * inv;
    // mean over heads: lane l (head0, dims 4l..) pairs with lane l^4 (head1)
    float o0 = 0.5f * (v0 + __shfl_xor(v0, 4));
    float o1 = 0.5f * (v1 + __shfl_xor(v1, 4));
    float o2 = 0.5f * (v2 + __shfl_xor(v2, 4));
    float o3 = 0.5f * (v3 + __shfl_xor(v3, 4));
    if (g == 0 && l < 4) {
        float4 o;
        o.x = o0 + b2[4*l+0]; o.y = o1 + b2[4*l+1];
        o.z = o2 + b2[4*l+2]; o.w = o3 + b2[4*l+3];
        *(float4*)(hf + (size_t)node * 16 + 4 * l) = o;
    }
}

// ---------------- Pooling + FC ----------------

__global__ __launch_bounds__(256) void pool_kernel(
    const float* __restrict__ hf, const int* __restrict__ batch,
    float* __restrict__ sums, float* __restrict__ counts, int n)
{
    int t = threadIdx.x;
    int d = t & 15, j = t >> 4;
    int base = blockIdx.x * 256 + j * 16;
    float run = 0.f, cnt = 0.f;
    int cg = -1;
    for (int i = 0; i < 16; ++i) {
        int nn = base + i;
        if (nn >= n) break;
        int g = batch[nn];
        if (g != cg) {
            if (cg >= 0) { atomicAdd(&sums[cg * 16 + d], run); if (d == 0) atomicAdd(&counts[cg], cnt); }
            cg = g; run = 0.f; cnt = 0.f;
        }
        run += hf[(size_t)nn * 16 + d];
        cnt += 1.f;
    }
    if (cg >= 0) { atomicAdd(&sums[cg * 16 + d], run); if (d == 0) atomicAdd(&counts[cg], cnt); }
}

__global__ void final_kernel(const float* __restrict__ sums, const float* __restrict__ counts,
                             const float* __restrict__ fcW, const float* __restrict__ fcb,
                             float* __restrict__ out, int G)
{
    int g = blockIdx.x * 64 + threadIdx.x;
    if (g < G) {
        float c = fmaxf(counts[g], 1.f);
        float s = 0.f;
        for (int dd = 0; dd < 16; ++dd) s += (sums[g * 16 + dd] / c) * fcW[dd];
        out[g] = s + fcb[0];
    }
}

// ---------------- launch ----------------

extern "C" void kernel_launch(void* const* d_in, const int* in_sizes, int n_in,
                              void* d_out, int out_size, void* d_ws, size_t ws_size,
                              hipStream_t stream)
{
    const float* x      = (const float*)d_in[0];
    const int*   ei     = (const int*)d_in[1];
    const int*   batch  = (const int*)d_in[2];
    const float* W1     = (const float*)d_in[3];
    const float* a_src1 = (const float*)d_in[4];
    const float* a_dst1 = (const float*)d_in[5];
    const float* b1     = (const float*)d_in[6];
    const float* W2     = (const float*)d_in[7];
    const float* a_src2 = (const float*)d_in[8];
    const float* a_dst2 = (const float*)d_in[9];
    const float* b2     = (const float*)d_in[10];
    const float* fcW    = (const float*)d_in[11];
    const float* fcb    = (const float*)d_in[12];
    float* out = (float*)d_out;

    int n = in_sizes[0] / 128;
    int E = in_sizes[1] / 2;
    int G = out_size;
    const int* srcA = ei;
    const int* dstA = ei + E;

    int nb = (n + (1 << CSR_SHIFT) - 1) >> CSR_SHIFT;
    int chunk = (E + CSR_NBLK - 1) / CSR_NBLK;

    char* p = (char*)d_ws;
    auto alloc = [&](size_t bytes) { char* r = p; p += (bytes + 255) & ~(size_t)255; return r; };
    int*   blockCntT  = (int*)alloc((size_t)nb * CSR_NBLK * 4);
    int*   tot        = (int*)alloc((size_t)nb * 4);
    int*   bucketBase = (int*)alloc((size_t)(nb + 1) * 4);
    int*   rowptr     = (int*)alloc((size_t)(n + 1) * 4);
    int*   csr        = (int*)alloc((size_t)E * 4);
    uint*  h1q        = (uint*)alloc((size_t)n * 32 * 4);    // fp8 x4 per uint
    float* as1        = (float*)alloc((size_t)n * 16);
    float* ad1        = (float*)alloc((size_t)n * 16);
    float* hrelu      = (float*)alloc((size_t)n * 128 * 4);  // fp32 (R8 best)
    uint*  h2q        = (uint*)alloc((size_t)n * 16 * 4);    // bf16 x2 per uint
    float* as2        = (float*)alloc((size_t)n * 8);
    float* ad2        = (float*)alloc((size_t)n * 8);
    float* hf         = (float*)alloc((size_t)n * 16 * 4);
    float* sums       = (float*)alloc((size_t)(G * 16 + G) * 4);
    float* counts     = sums + G * 16;

    // edge staging buffer aliases hrelu; consumed by local_csr before agg1 writes.
    uint* ebuf = (uint*)hrelu;

    hipMemsetAsync(sums, 0, (size_t)(G * 16 + G) * 4, stream);

    bucket_count_kernel<<<CSR_NBLK, 256, 0, stream>>>(dstA, E, chunk, nb, blockCntT);
    row_scan_kernel<<<nb, 512, 0, stream>>>(blockCntT, tot);
    total_scan_kernel<<<1, 1024, 0, stream>>>(tot, nb, bucketBase);
    bucket_scatter_kernel<<<CSR_NBLK, 256, 0, stream>>>(srcA, dstA, E, chunk, nb,
                                                        blockCntT, bucketBase, ebuf);
    local_csr_kernel<<<nb, 256, 0, stream>>>(ebuf, bucketBase, n, E, rowptr, csr);

    int gb = (n + 127) / 128;
    gemm_alpha_kernel<128, 4><<<gb, 256, 0, stream>>>(x, W1, a_src1, a_dst1, h1q, as1, ad1, n);
    agg1_kernel<<<(n + 3) / 4, 256, 0, stream>>>(as1, ad1, h1q, rowptr, csr, b1, hrelu, n);
    gemm_alpha_kernel<32, 2><<<gb, 256, 0, stream>>>(hrelu, W2, a_src2, a_dst2, h2q, as2, ad2, n);
    agg2_kernel<<<(n + 3) / 4, 256, 0, stream>>>(as2, ad2, h2q, rowptr, csr, b2, hf, n);
    pool_kernel<<<(n + 255) / 256, 256, 0, stream>>>(hf, batch, sums, counts, n);
    final_kernel<<<1, 64, 0, stream>>>(sums, counts, fcW, fcb, out, G);
}

// Round 14
// 197.655 us; speedup vs baseline: 1.2896x; 1.0207x over previous
//
#include <hip/hip_runtime.h>

#define LRELU(x) ((x) > 0.f ? (x) : 0.2f*(x))
typedef unsigned int uint;
typedef unsigned short ushort;
typedef _Float16 half2_t __attribute__((ext_vector_type(2)));

__device__ inline ushort f2bf(float f) {
    union { float f; unsigned u; } v; v.f = f;
    unsigned r = v.u + 0x7FFF + ((v.u >> 16) & 1);
    return (ushort)(r >> 16);
}
__device__ inline uint packbf(float a, float b) {
    return (uint)f2bf(a) | ((uint)f2bf(b) << 16);
}
__device__ inline float bflo(uint u){ union{uint u; float f;}v; v.u = u<<16; return v.f; }
__device__ inline float bfhi(uint u){ union{uint u; float f;}v; v.u = u & 0xFFFF0000u; return v.f; }
__device__ inline half2_t u2h(uint u){ union{uint u; half2_t h;}v; v.u=u; return v.h; }
__device__ inline uint h2u(half2_t h){ union{half2_t h; uint u;}v; v.h=h; return v.u; }
__device__ inline uint packh(float a, float b){
    half2_t h; h.x = (_Float16)a; h.y = (_Float16)b; return h2u(h);
}

// ---------------- CSR build: atomic-free two-level bucket sort ----------------
// ebuf entries packed: (src << 7) | (dst & 127)
// Scan kept as TWO kernels deliberately — fused last-block version needs
// agent-scope __threadfence() = L2 writeback on multi-XCD gfx950 (~60us, R10).

#define CSR_SHIFT 7
#define CSR_NBLK  512

__global__ __launch_bounds__(256) void bucket_count_kernel(
    const int* __restrict__ dst, int E, int chunk, int nb,
    int* __restrict__ blockCntT)
{
    __shared__ int cnt[1024];
    int t = threadIdx.x, k = blockIdx.x;
    for (int i = t; i < nb; i += 256) cnt[i] = 0;
    __syncthreads();
    int e0 = k * chunk, e1 = min(e0 + chunk, E);
    for (int e = e0 + t; e < e1; e += 256)
        atomicAdd(&cnt[dst[e] >> CSR_SHIFT], 1);
    __syncthreads();
    for (int b = t; b < nb; b += 256)
        blockCntT[b * CSR_NBLK + k] = cnt[b];
}

__global__ __launch_bounds__(512) void row_scan_kernel(
    int* __restrict__ blockCntT, int* __restrict__ tot)
{
    __shared__ int sm[512];
    int b = blockIdx.x, t = threadIdx.x;
    int* row = blockCntT + b * CSR_NBLK;
    int v = row[t];
    sm[t] = v;
    __syncthreads();
    for (int off = 1; off < 512; off <<= 1) {
        int u = (t >= off) ? sm[t - off] : 0;
        __syncthreads(); sm[t] += u; __syncthreads();
    }
    row[t] = sm[t] - v;            // exclusive within bucket
    if (t == 511) tot[b] = sm[511];
}

__global__ __launch_bounds__(1024) void total_scan_kernel(
    const int* __restrict__ tot, int nb, int* __restrict__ bucketBase)
{
    __shared__ int sm[1024];
    int t = threadIdx.x;
    int v = (t < nb) ? tot[t] : 0;
    sm[t] = v;
    __syncthreads();
    for (int off = 1; off < 1024; off <<= 1) {
        int u = (t >= off) ? sm[t - off] : 0;
        __syncthreads(); sm[t] += u; __syncthreads();
    }
    if (t < nb) bucketBase[t] = sm[t] - v;
    if (t == 1023) bucketBase[nb] = sm[1023];
}

__global__ __launch_bounds__(256) void bucket_scatter_kernel(
    const int* __restrict__ src, const int* __restrict__ dst, int E, int chunk, int nb,
    const int* __restrict__ blockCntT, const int* __restrict__ bucketBase,
    uint* __restrict__ ebuf)
{
    __shared__ int cur[1024];
    int t = threadIdx.x, k = blockIdx.x;
    for (int b = t; b < nb; b += 256)
        cur[b] = bucketBase[b] + blockCntT[b * CSR_NBLK + k];
    __syncthreads();
    int e0 = k * chunk, e1 = min(e0 + chunk, E);
    for (int e = e0 + t; e < e1; e += 256) {
        int d = dst[e], s_ = src[e];
        int pos = atomicAdd(&cur[d >> CSR_SHIFT], 1);
        ebuf[pos] = ((uint)s_ << 7) | (uint)(d & 127);
    }
}

__global__ __launch_bounds__(256) void local_csr_kernel(
    const uint* __restrict__ ebuf, const int* __restrict__ bucketBase,
    int n, int E, int* __restrict__ rowptr, int* __restrict__ csr)
{
    __shared__ int lbase[1 << CSR_SHIFT];
    __shared__ int lcur[1 << CSR_SHIFT];
    __shared__ int ldeg[1 << CSR_SHIFT];
    int b = blockIdx.x, t = threadIdx.x;
    int n0 = b << CSR_SHIFT;
    int base = bucketBase[b], end = bucketBase[b + 1];
    if (t < (1 << CSR_SHIFT)) ldeg[t] = 0;
    __syncthreads();
    for (int e = base + t; e < end; e += 256)
        atomicAdd(&ldeg[ebuf[e] & 127], 1);
    __syncthreads();
    if (t == 0) {
        int run = base;
        for (int i = 0; i < (1 << CSR_SHIFT); ++i) {
            lbase[i] = run; lcur[i] = run; run += ldeg[i];
        }
    }
    __syncthreads();
    int node = n0 + t;
    if (t < (1 << CSR_SHIFT) && node < n) rowptr[node] = lbase[t];
    if (b == 0 && t == 0) rowptr[n] = E;
    for (int e = base + t; e < end; e += 256) {
        uint ed = ebuf[e];
        int pos = atomicAdd(&lcur[ed & 127], 1);
        csr[pos] = (int)(ed >> 7);
    }
}

// ---------------- GEMM + fused alpha dots (f16 dot2, swizzled LDS) -------------
// W staged in LDS as f16 K-PAIRS: WLH[k2][slot] (uint4 granularity), with
// bit-rotation swizzle p = ((s&3)<<3)|(s>>2) for COLS=128 so the 8 col-threads
// read 8 CONSECUTIVE uint4 (=128B, all 32 banks) per j -> conflict-free
// (R13 measured 1.6M conflict cycles without it). NPT=2 -> grid 782 blocks
// (~3 blocks/CU) to fix the 12% occupancy of NPT=4's 391-block grid.

template<int COLS, int HEADS>
__global__ __launch_bounds__(256) void gemm_alpha_kernel(
    const float* __restrict__ x, const float* __restrict__ W,
    const float* __restrict__ a_src, const float* __restrict__ a_dst,
    uint* __restrict__ hq, float* __restrict__ as_out,
    float* __restrict__ ad_out, int n)
{
    constexpr int K = 128;
    constexpr int K2 = K / 2;
    constexpr int CPT = COLS / 8;       // cols per thread (16 or 4)
    constexpr int NPT = 2;
    constexpr int DIM = COLS / HEADS;
    constexpr int TPH = DIM / CPT;      // 2 or 4
    constexpr int NSLOT4 = COLS / 4;    // uint4 slots per k2-row
    __shared__ uint WLH[K2 * COLS];     // f16x2 per uint

    int t = threadIdx.x;
    for (int sid = t; sid < K2 * NSLOT4; sid += 256) {
        int k2 = sid / NSLOT4, s = sid % NSLOT4;
        int c = s * 4;
        float4 w0 = *(const float4*)(W + (2 * k2) * COLS + c);
        float4 w1 = *(const float4*)(W + (2 * k2 + 1) * COLS + c);
        uint4 u;
        u.x = packh(w0.x, w1.x);
        u.y = packh(w0.y, w1.y);
        u.z = packh(w0.z, w1.z);
        u.w = packh(w0.w, w1.w);
        int p = (COLS == 128) ? (((s & 3) << 3) | (s >> 2)) : s;   // bijective swizzle
        ((uint4*)WLH)[k2 * NSLOT4 + p] = u;
    }
    __syncthreads();

    int m_ = t & 7;
    int node0 = blockIdx.x * (32 * NPT) + (t >> 3) * NPT;
    if (node0 >= n) return;
    int c0 = m_ * CPT;

    size_t rows[NPT];
#pragma unroll
    for (int i = 0; i < NPT; i++) rows[i] = (size_t)min(node0 + i, n - 1);

    float acc[NPT][CPT];
#pragma unroll
    for (int i = 0; i < NPT; i++)
#pragma unroll
        for (int q = 0; q < CPT; q++) acc[i][q] = 0.f;

    for (int k4 = 0; k4 < K; k4 += 4) {     // 4 k-values = 2 k2-pairs per iter
        half2_t xp[NPT][2];
#pragma unroll
        for (int i = 0; i < NPT; i++) {
            float4 v = *(const float4*)(x + rows[i] * K + k4);
            half2_t h0; h0.x = (_Float16)v.x; h0.y = (_Float16)v.y;
            half2_t h1; h1.x = (_Float16)v.z; h1.y = (_Float16)v.w;
            xp[i][0] = h0;
            xp[i][1] = h1;
        }
#pragma unroll
        for (int p = 0; p < 2; p++) {
            int k2 = (k4 >> 1) + p;
#pragma unroll
            for (int j = 0; j < CPT / 4; j++) {
                // logical slot s = m_*(CPT/4)+j; swizzled: (j<<3)|m_ for COLS=128
                int slot = (COLS == 128) ? ((j << 3) | m_) : m_;
                uint4 wq = ((const uint4*)WLH)[k2 * NSLOT4 + slot];
                half2_t w0 = u2h(wq.x), w1 = u2h(wq.y), w2 = u2h(wq.z), w3 = u2h(wq.w);
#pragma unroll
                for (int i = 0; i < NPT; i++) {
                    half2_t xv = xp[i][p];
                    acc[i][j*4+0] = __builtin_amdgcn_fdot2(xv, w0, acc[i][j*4+0], false);
                    acc[i][j*4+1] = __builtin_amdgcn_fdot2(xv, w1, acc[i][j*4+1], false);
                    acc[i][j*4+2] = __builtin_amdgcn_fdot2(xv, w2, acc[i][j*4+2], false);
                    acc[i][j*4+3] = __builtin_amdgcn_fdot2(xv, w3, acc[i][j*4+3], false);
                }
            }
        }
    }

    int head = c0 / DIM, lc = c0 - head * DIM;
    float asc[CPT], adc[CPT];
#pragma unroll
    for (int q = 0; q < CPT; q++) {
        asc[q] = a_src[head * DIM + lc + q];
        adc[q] = a_dst[head * DIM + lc + q];
    }

#pragma unroll
    for (int i = 0; i < NPT; i++) {
        int node = node0 + i;
        if (node >= n) break;
        if constexpr (COLS == 128) {
            uint wds[4];
#pragma unroll
            for (int j = 0; j < 4; j++) {
                int u = 0;
                u = __builtin_amdgcn_cvt_pk_fp8_f32(acc[i][j*4+0], acc[i][j*4+1], u, false);
                u = __builtin_amdgcn_cvt_pk_fp8_f32(acc[i][j*4+2], acc[i][j*4+3], u, true);
                wds[j] = (uint)u;
            }
            *(uint4*)(hq + (size_t)node * 32 + m_ * 4) = make_uint4(wds[0], wds[1], wds[2], wds[3]);
        } else {
            uint w0 = packbf(acc[i][0], acc[i][1]);
            uint w1 = packbf(acc[i][2], acc[i][3]);
            *(uint2*)(hq + (size_t)node * 16 + m_ * 2) = make_uint2(w0, w1);
        }
        float ps = 0.f, pd = 0.f;
#pragma unroll
        for (int q = 0; q < CPT; q++) {
            ps += acc[i][q] * asc[q];
            pd += acc[i][q] * adc[q];
        }
#pragma unroll
        for (int off = 1; off < TPH; off <<= 1) {
            ps += __shfl_xor(ps, off);
            pd += __shfl_xor(pd, off);
        }
        if ((m_ & (TPH - 1)) == 0) {
            as_out[node * HEADS + head] = ps;
            ad_out[node * HEADS + head] = pd;
        }
    }
}

// ---------------- Layer-1 aggregation (flat, fp8 gather — R8 best) ------------
// One wave per node; no LDS/barriers. 8 groups x 8 lanes; group g owns edges
// rp+g+8k. Lane: head=l>>1, dims 16l..16l+15 (uint4 = 16 fp8).

__global__ __launch_bounds__(256) void agg1_kernel(
    const float* __restrict__ as1f, const float* __restrict__ ad1f,
    const uint* __restrict__ h1q, const int* __restrict__ rowptr,
    const int* __restrict__ csr, const float* __restrict__ b1,
    float* __restrict__ hout, int n)
{
    int t = threadIdx.x;
    int w = t >> 6, tw = t & 63;
    int g = tw >> 3, l = tw & 7;   // 8 groups x 8 lanes
    int head = l >> 1;
    int node = blockIdx.x * 4 + w;
    if (node >= n) return;

    float adh = ad1f[node * 4 + head];
    int rp = rowptr[node], re = rowptr[node + 1];

    float acc[16];
#pragma unroll
    for (int i = 0; i < 16; i++) acc[i] = 0.f;
    float den = 0.f;

#pragma unroll 2
    for (int e = rp + g; e < re; e += 8) {
        int s = csr[e];
        float a = as1f[s * 4 + head];
        uint4 u = *(const uint4*)(h1q + ((size_t)s << 5) + (l << 2));
        float ex = __expf(LRELU(a + adh));
        den += ex;
        uint ua[4] = {u.x, u.y, u.z, u.w};
#pragma unroll
        for (int j = 0; j < 4; j++) {
            auto p0 = __builtin_amdgcn_cvt_pk_f32_fp8(ua[j], false);
            auto p1 = __builtin_amdgcn_cvt_pk_f32_fp8(ua[j], true);
            acc[j*4+0] += ex * p0[0]; acc[j*4+1] += ex * p0[1];
            acc[j*4+2] += ex * p1[0]; acc[j*4+3] += ex * p1[1];
        }
    }

    if (g == 0) {   // self loop, counted once (pre-reduction)
        float a = as1f[node * 4 + head];
        float ex = __expf(LRELU(a + adh));
        den += ex;
        uint4 u = *(const uint4*)(h1q + ((size_t)node << 5) + (l << 2));
        uint ua[4] = {u.x, u.y, u.z, u.w};
#pragma unroll
        for (int j = 0; j < 4; j++) {
            auto p0 = __builtin_amdgcn_cvt_pk_f32_fp8(ua[j], false);
            auto p1 = __builtin_amdgcn_cvt_pk_f32_fp8(ua[j], true);
            acc[j*4+0] += ex * p0[0]; acc[j*4+1] += ex * p0[1];
            acc[j*4+2] += ex * p1[0]; acc[j*4+3] += ex * p1[1];
        }
    }

    // reduce across the 8 groups (lane-id bits 3,4,5)
#pragma unroll
    for (int i = 0; i < 16; i++) {
        acc[i] += __shfl_xor(acc[i], 8);
        acc[i] += __shfl_xor(acc[i], 16);
        acc[i] += __shfl_xor(acc[i], 32);
    }
    den += __shfl_xor(den, 8);
    den += __shfl_xor(den, 16);
    den += __shfl_xor(den, 32);

    if (g == 0) {
        float inv = 1.f / (den + 1e-16f);
        const float4* b4 = (const float4*)b1;
#pragma unroll
        for (int j = 0; j < 4; j++) {
            float4 bv = b4[(l << 2) + j];
            float4 o;
            o.x = fmaxf(acc[j*4+0] * inv + bv.x, 0.f);
            o.y = fmaxf(acc[j*4+1] * inv + bv.y, 0.f);
            o.z = fmaxf(acc[j*4+2] * inv + bv.z, 0.f);
            o.w = fmaxf(acc[j*4+3] * inv + bv.w, 0.f);
            ((float4*)hout)[(size_t)node * 32 + (l << 2) + j] = o;
        }
    }
}

// ---------------- Layer-2 aggregation (flat, bf16 gather, head-mean — R8) -----

__global__ __launch_bounds__(256) void agg2_kernel(
    const float* __restrict__ as2f, const float* __restrict__ ad2f,
    const uint* __restrict__ h2q, const int* __restrict__ rowptr,
    const int* __restrict__ csr, const float* __restrict__ b2,
    float* __restrict__ hf, int n)
{
    int t = threadIdx.x;
    int w = t >> 6, tw = t & 63;
    int g = tw >> 3, l = tw & 7;
    int head = l >> 2;
    int node = blockIdx.x * 4 + w;
    if (node >= n) return;

    float adh = ad2f[node * 2 + head];
    int rp = rowptr[node], re = rowptr[node + 1];

    float acc[4] = {0.f, 0.f, 0.f, 0.f};
    float den = 0.f;

#pragma unroll 2
    for (int e = rp + g; e < re; e += 8) {
        int s = csr[e];
        float a = as2f[s * 2 + head];
        uint2 u = *(const uint2*)(h2q + ((size_t)s << 4) + (l << 1));
        float ex = __expf(LRELU(a + adh));
        den += ex;
        acc[0] += ex * bflo(u.x); acc[1] += ex * bfhi(u.x);
        acc[2] += ex * bflo(u.y); acc[3] += ex * bfhi(u.y);
    }

    if (g == 0) {   // self loop
        float a = as2f[node * 2 + head];
        float ex = __expf(LRELU(a + adh));
        den += ex;
        uint2 u = *(const uint2*)(h2q + ((size_t)node << 4) + (l << 1));
        acc[0] += ex * bflo(u.x); acc[1] += ex * bfhi(u.x);
        acc[2] += ex * bflo(u.y); acc[3] += ex * bfhi(u.y);
    }

#pragma unroll
    for (int i = 0; i < 4; i++) {
        acc[i] += __shfl_xor(acc[i], 8);
        acc[i] += __shfl_xor(acc[i], 16);
        acc[i] += __shfl_xor(acc[i], 32);
    }
    den += __shfl_xor(den, 8);
    den += __shfl_xor(den, 16);
    den += __shfl_xor(den, 32);

    float inv = 1.f / (den + 1e-16f);
    float v0 = acc[0] * inv, v1 = acc[1] * inv, v2 = acc[2] * inv, v3 = acc[3] * inv;
    // mean over heads: lane l (head0, dims 4l..) pairs with lane l^4 (head1)
    float o0 = 0.5f * (v0 + __shfl_xor(v0, 4));
    float o1 = 0.5f * (v1 + __shfl_xor(v1, 4));
    float o2 = 0.5f * (v2 + __shfl_xor(v2, 4));
    float o3 = 0.5f * (v3 + __shfl_xor(v3, 4));
    if (g == 0 && l < 4) {
        float4 o;
        o.x = o0 + b2[4*l+0]; o.y = o1 + b2[4*l+1];
        o.z = o2 + b2[4*l+2]; o.w = o3 + b2[4*l+3];
        *(float4*)(hf + (size_t)node * 16 + 4 * l) = o;
    }
}

// ---------------- Pooling + FC ----------------

__global__ __launch_bounds__(256) void pool_kernel(
    const float* __restrict__ hf, const int* __restrict__ batch,
    float* __restrict__ sums, float* __restrict__ counts, int n)
{
    int t = threadIdx.x;
    int d = t & 15, j = t >> 4;
    int base = blockIdx.x * 256 + j * 16;
    float run = 0.f, cnt = 0.f;
    int cg = -1;
    for (int i = 0; i < 16; ++i) {
        int nn = base + i;
        if (nn >= n) break;
        int g = batch[nn];
        if (g != cg) {
            if (cg >= 0) { atomicAdd(&sums[cg * 16 + d], run); if (d == 0) atomicAdd(&counts[cg], cnt); }
            cg = g; run = 0.f; cnt = 0.f;
        }
        run += hf[(size_t)nn * 16 + d];
        cnt += 1.f;
    }
    if (cg >= 0) { atomicAdd(&sums[cg * 16 + d], run); if (d == 0) atomicAdd(&counts[cg], cnt); }
}

__global__ void final_kernel(const float* __restrict__ sums, const float* __restrict__ counts,
                             const float* __restrict__ fcW, const float* __restrict__ fcb,
                             float* __restrict__ out, int G)
{
    int g = blockIdx.x * 64 + threadIdx.x;
    if (g < G) {
        float c = fmaxf(counts[g], 1.f);
        float s = 0.f;
        for (int dd = 0; dd < 16; ++dd) s += (sums[g * 16 + dd] / c) * fcW[dd];
        out[g] = s + fcb[0];
    }
}

// ---------------- launch ----------------

extern "C" void kernel_launch(void* const* d_in, const int* in_sizes, int n_in,
                              void* d_out, int out_size, void* d_ws, size_t ws_size,
                              hipStream_t stream)
{
    const float* x      = (const float*)d_in[0];
    const int*   ei     = (const int*)d_in[1];
    const int*   batch  = (const int*)d_in[2];
    const float* W1     = (const float*)d_in[3];
    const float* a_src1 = (const float*)d_in[4];
    const float* a_dst1 = (const float*)d_in[5];
    const float* b1     = (const float*)d_in[6];
    const float* W2     = (const float*)d_in[7];
    const float* a_src2 = (const float*)d_in[8];
    const float* a_dst2 = (const float*)d_in[9];
    const float* b2     = (const float*)d_in[10];
    const float* fcW    = (const float*)d_in[11];
    const float* fcb    = (const float*)d_in[12];
    float* out = (float*)d_out;

    int n = in_sizes[0] / 128;
    int E = in_sizes[1] / 2;
    int G = out_size;
    const int* srcA = ei;
    const int* dstA = ei + E;

    int nb = (n + (1 << CSR_SHIFT) - 1) >> CSR_SHIFT;
    int chunk = (E + CSR_NBLK - 1) / CSR_NBLK;

    char* p = (char*)d_ws;
    auto alloc = [&](size_t bytes) { char* r = p; p += (bytes + 255) & ~(size_t)255; return r; };
    int*   blockCntT  = (int*)alloc((size_t)nb * CSR_NBLK * 4);
    int*   tot        = (int*)alloc((size_t)nb * 4);
    int*   bucketBase = (int*)alloc((size_t)(nb + 1) * 4);
    int*   rowptr     = (int*)alloc((size_t)(n + 1) * 4);
    int*   csr        = (int*)alloc((size_t)E * 4);
    uint*  h1q        = (uint*)alloc((size_t)n * 32 * 4);    // fp8 x4 per uint
    float* as1        = (float*)alloc((size_t)n * 16);
    float* ad1        = (float*)alloc((size_t)n * 16);
    float* hrelu      = (float*)alloc((size_t)n * 128 * 4);  // fp32 (R8 best)
    uint*  h2q        = (uint*)alloc((size_t)n * 16 * 4);    // bf16 x2 per uint
    float* as2        = (float*)alloc((size_t)n * 8);
    float* ad2        = (float*)alloc((size_t)n * 8);
    float* hf         = (float*)alloc((size_t)n * 16 * 4);
    float* sums       = (float*)alloc((size_t)(G * 16 + G) * 4);
    float* counts     = sums + G * 16;

    // edge staging buffer aliases hrelu; consumed by local_csr before agg1 writes.
    uint* ebuf = (uint*)hrelu;

    hipMemsetAsync(sums, 0, (size_t)(G * 16 + G) * 4, stream);

    bucket_count_kernel<<<CSR_NBLK, 256, 0, stream>>>(dstA, E, chunk, nb, blockCntT);
    row_scan_kernel<<<nb, 512, 0, stream>>>(blockCntT, tot);
    total_scan_kernel<<<1, 1024, 0, stream>>>(tot, nb, bucketBase);
    bucket_scatter_kernel<<<CSR_NBLK, 256, 0, stream>>>(srcA, dstA, E, chunk, nb,
                                                        blockCntT, bucketBase, ebuf);
    local_csr_kernel<<<nb, 256, 0, stream>>>(ebuf, bucketBase, n, E, rowptr, csr);

    int gb = (n + 63) / 64;   // NPT=2: 64 nodes per block
    gemm_alpha_kernel<128, 4><<<gb, 256, 0, stream>>>(x, W1, a_src1, a_dst1, h1q, as1, ad1, n);
    agg1_kernel<<<(n + 3) / 4, 256, 0, stream>>>(as1, ad1, h1q, rowptr, csr, b1, hrelu, n);
    gemm_alpha_kernel<32, 2><<<gb, 256, 0, stream>>>(hrelu, W2, a_src2, a_dst2, h2q, as2, ad2, n);
    agg2_kernel<<<(n + 3) / 4, 256, 0, stream>>>(as2, ad2, h2q, rowptr, csr, b2, hf, n);
    pool_kernel<<<(n + 255) / 256, 256, 0, stream>>>(hf, batch, sums, counts, n);
    final_kernel<<<1, 64, 0, stream>>>(sums, counts, fcW, fcb, out, G);
}

// Round 15
// 194.005 us; speedup vs baseline: 1.3138x; 1.0188x over previous
//
#include <hip/hip_runtime.h>

#define LRELU(x) ((x) > 0.f ? (x) : 0.2f*(x))
typedef unsigned int uint;
typedef unsigned short ushort;
typedef _Float16 half2_t __attribute__((ext_vector_type(2)));

__device__ inline ushort f2bf(float f) {
    union { float f; unsigned u; } v; v.f = f;
    unsigned r = v.u + 0x7FFF + ((v.u >> 16) & 1);
    return (ushort)(r >> 16);
}
__device__ inline uint packbf(float a, float b) {
    return (uint)f2bf(a) | ((uint)f2bf(b) << 16);
}
__device__ inline float bflo(uint u){ union{uint u; float f;}v; v.u = u<<16; return v.f; }
__device__ inline float bfhi(uint u){ union{uint u; float f;}v; v.u = u & 0xFFFF0000u; return v.f; }
__device__ inline half2_t u2h(uint u){ union{uint u; half2_t h;}v; v.u=u; return v.h; }
__device__ inline uint h2u(half2_t h){ union{half2_t h; uint u;}v; v.h=h; return v.u; }
__device__ inline uint packh(float a, float b){
    half2_t h; h.x = (_Float16)a; h.y = (_Float16)b; return h2u(h);
}

// ---------------- CSR build: atomic-free two-level bucket sort ----------------
// ebuf entries packed: (src << 7) | (dst & 127)
// Scan kept as TWO kernels deliberately — fused last-block version needs
// agent-scope __threadfence() = L2 writeback on multi-XCD gfx950 (~60us, R10).

#define CSR_SHIFT 7
#define CSR_NBLK  512

__global__ __launch_bounds__(256) void bucket_count_kernel(
    const int* __restrict__ dst, int E, int chunk, int nb,
    int* __restrict__ blockCntT)
{
    __shared__ int cnt[1024];
    int t = threadIdx.x, k = blockIdx.x;
    for (int i = t; i < nb; i += 256) cnt[i] = 0;
    __syncthreads();
    int e0 = k * chunk, e1 = min(e0 + chunk, E);
    for (int e = e0 + t; e < e1; e += 256)
        atomicAdd(&cnt[dst[e] >> CSR_SHIFT], 1);
    __syncthreads();
    for (int b = t; b < nb; b += 256)
        blockCntT[b * CSR_NBLK + k] = cnt[b];
}

__global__ __launch_bounds__(512) void row_scan_kernel(
    int* __restrict__ blockCntT, int* __restrict__ tot)
{
    __shared__ int sm[512];
    int b = blockIdx.x, t = threadIdx.x;
    int* row = blockCntT + b * CSR_NBLK;
    int v = row[t];
    sm[t] = v;
    __syncthreads();
    for (int off = 1; off < 512; off <<= 1) {
        int u = (t >= off) ? sm[t - off] : 0;
        __syncthreads(); sm[t] += u; __syncthreads();
    }
    row[t] = sm[t] - v;            // exclusive within bucket
    if (t == 511) tot[b] = sm[511];
}

__global__ __launch_bounds__(1024) void total_scan_kernel(
    const int* __restrict__ tot, int nb, int* __restrict__ bucketBase)
{
    __shared__ int sm[1024];
    int t = threadIdx.x;
    int v = (t < nb) ? tot[t] : 0;
    sm[t] = v;
    __syncthreads();
    for (int off = 1; off < 1024; off <<= 1) {
        int u = (t >= off) ? sm[t - off] : 0;
        __syncthreads(); sm[t] += u; __syncthreads();
    }
    if (t < nb) bucketBase[t] = sm[t] - v;
    if (t == 1023) bucketBase[nb] = sm[1023];
}

__global__ __launch_bounds__(256) void bucket_scatter_kernel(
    const int* __restrict__ src, const int* __restrict__ dst, int E, int chunk, int nb,
    const int* __restrict__ blockCntT, const int* __restrict__ bucketBase,
    uint* __restrict__ ebuf)
{
    __shared__ int cur[1024];
    int t = threadIdx.x, k = blockIdx.x;
    for (int b = t; b < nb; b += 256)
        cur[b] = bucketBase[b] + blockCntT[b * CSR_NBLK + k];
    __syncthreads();
    int e0 = k * chunk, e1 = min(e0 + chunk, E);
    for (int e = e0 + t; e < e1; e += 256) {
        int d = dst[e], s_ = src[e];
        int pos = atomicAdd(&cur[d >> CSR_SHIFT], 1);
        ebuf[pos] = ((uint)s_ << 7) | (uint)(d & 127);
    }
}

__global__ __launch_bounds__(256) void local_csr_kernel(
    const uint* __restrict__ ebuf, const int* __restrict__ bucketBase,
    int n, int E, int* __restrict__ rowptr, int* __restrict__ csr)
{
    __shared__ int lbase[1 << CSR_SHIFT];
    __shared__ int lcur[1 << CSR_SHIFT];
    __shared__ int ldeg[1 << CSR_SHIFT];
    int b = blockIdx.x, t = threadIdx.x;
    int n0 = b << CSR_SHIFT;
    int base = bucketBase[b], end = bucketBase[b + 1];
    if (t < (1 << CSR_SHIFT)) ldeg[t] = 0;
    __syncthreads();
    for (int e = base + t; e < end; e += 256)
        atomicAdd(&ldeg[ebuf[e] & 127], 1);
    __syncthreads();
    if (t == 0) {
        int run = base;
        for (int i = 0; i < (1 << CSR_SHIFT); ++i) {
            lbase[i] = run; lcur[i] = run; run += ldeg[i];
        }
    }
    __syncthreads();
    int node = n0 + t;
    if (t < (1 << CSR_SHIFT) && node < n) rowptr[node] = lbase[t];
    if (b == 0 && t == 0) rowptr[n] = E;
    for (int e = base + t; e < end; e += 256) {
        uint ed = ebuf[e];
        int pos = atomicAdd(&lcur[ed & 127], 1);
        csr[pos] = (int)(ed >> 7);
    }
}

// ---------------- GEMM + fused alpha dots (f16 dot2, swizzled LDS) -------------
// W staged in LDS as f16 K-PAIRS; bit-rotation swizzle for COLS=128 keeps the
// 8 col-threads on 8 consecutive uint4 (=all 32 banks) per j. NPT=2 for grid
// occupancy. Output: fp8 e4m3 packed rows for BOTH layers (32B row for COLS=32,
// 128B row for COLS=128).

template<int COLS, int HEADS>
__global__ __launch_bounds__(256) void gemm_alpha_kernel(
    const float* __restrict__ x, const float* __restrict__ W,
    const float* __restrict__ a_src, const float* __restrict__ a_dst,
    uint* __restrict__ hq, float* __restrict__ as_out,
    float* __restrict__ ad_out, int n)
{
    constexpr int K = 128;
    constexpr int K2 = K / 2;
    constexpr int CPT = COLS / 8;       // cols per thread (16 or 4)
    constexpr int NPT = 2;
    constexpr int DIM = COLS / HEADS;
    constexpr int TPH = DIM / CPT;      // 2 or 4
    constexpr int NSLOT4 = COLS / 4;    // uint4 slots per k2-row
    __shared__ uint WLH[K2 * COLS];     // f16x2 per uint

    int t = threadIdx.x;
    for (int sid = t; sid < K2 * NSLOT4; sid += 256) {
        int k2 = sid / NSLOT4, s = sid % NSLOT4;
        int c = s * 4;
        float4 w0 = *(const float4*)(W + (2 * k2) * COLS + c);
        float4 w1 = *(const float4*)(W + (2 * k2 + 1) * COLS + c);
        uint4 u;
        u.x = packh(w0.x, w1.x);
        u.y = packh(w0.y, w1.y);
        u.z = packh(w0.z, w1.z);
        u.w = packh(w0.w, w1.w);
        int p = (COLS == 128) ? (((s & 3) << 3) | (s >> 2)) : s;   // bijective swizzle
        ((uint4*)WLH)[k2 * NSLOT4 + p] = u;
    }
    __syncthreads();

    int m_ = t & 7;
    int node0 = blockIdx.x * (32 * NPT) + (t >> 3) * NPT;
    if (node0 >= n) return;
    int c0 = m_ * CPT;

    size_t rows[NPT];
#pragma unroll
    for (int i = 0; i < NPT; i++) rows[i] = (size_t)min(node0 + i, n - 1);

    float acc[NPT][CPT];
#pragma unroll
    for (int i = 0; i < NPT; i++)
#pragma unroll
        for (int q = 0; q < CPT; q++) acc[i][q] = 0.f;

    for (int k4 = 0; k4 < K; k4 += 4) {     // 4 k-values = 2 k2-pairs per iter
        half2_t xp[NPT][2];
#pragma unroll
        for (int i = 0; i < NPT; i++) {
            float4 v = *(const float4*)(x + rows[i] * K + k4);
            half2_t h0; h0.x = (_Float16)v.x; h0.y = (_Float16)v.y;
            half2_t h1; h1.x = (_Float16)v.z; h1.y = (_Float16)v.w;
            xp[i][0] = h0;
            xp[i][1] = h1;
        }
#pragma unroll
        for (int p = 0; p < 2; p++) {
            int k2 = (k4 >> 1) + p;
#pragma unroll
            for (int j = 0; j < CPT / 4; j++) {
                int slot = (COLS == 128) ? ((j << 3) | m_) : m_;
                uint4 wq = ((const uint4*)WLH)[k2 * NSLOT4 + slot];
                half2_t w0 = u2h(wq.x), w1 = u2h(wq.y), w2 = u2h(wq.z), w3 = u2h(wq.w);
#pragma unroll
                for (int i = 0; i < NPT; i++) {
                    half2_t xv = xp[i][p];
                    acc[i][j*4+0] = __builtin_amdgcn_fdot2(xv, w0, acc[i][j*4+0], false);
                    acc[i][j*4+1] = __builtin_amdgcn_fdot2(xv, w1, acc[i][j*4+1], false);
                    acc[i][j*4+2] = __builtin_amdgcn_fdot2(xv, w2, acc[i][j*4+2], false);
                    acc[i][j*4+3] = __builtin_amdgcn_fdot2(xv, w3, acc[i][j*4+3], false);
                }
            }
        }
    }

    int head = c0 / DIM, lc = c0 - head * DIM;
    float asc[CPT], adc[CPT];
#pragma unroll
    for (int q = 0; q < CPT; q++) {
        asc[q] = a_src[head * DIM + lc + q];
        adc[q] = a_dst[head * DIM + lc + q];
    }

#pragma unroll
    for (int i = 0; i < NPT; i++) {
        int node = node0 + i;
        if (node >= n) break;
        if constexpr (COLS == 128) {
            uint wds[4];
#pragma unroll
            for (int j = 0; j < 4; j++) {
                int u = 0;
                u = __builtin_amdgcn_cvt_pk_fp8_f32(acc[i][j*4+0], acc[i][j*4+1], u, false);
                u = __builtin_amdgcn_cvt_pk_fp8_f32(acc[i][j*4+2], acc[i][j*4+3], u, true);
                wds[j] = (uint)u;
            }
            *(uint4*)(hq + (size_t)node * 32 + m_ * 4) = make_uint4(wds[0], wds[1], wds[2], wds[3]);
        } else {
            // fp8 row: 8 uints per node (32 dims), one uint per col-thread
            int u = 0;
            u = __builtin_amdgcn_cvt_pk_fp8_f32(acc[i][0], acc[i][1], u, false);
            u = __builtin_amdgcn_cvt_pk_fp8_f32(acc[i][2], acc[i][3], u, true);
            hq[(size_t)node * 8 + m_] = (uint)u;
        }
        float ps = 0.f, pd = 0.f;
#pragma unroll
        for (int q = 0; q < CPT; q++) {
            ps += acc[i][q] * asc[q];
            pd += acc[i][q] * adc[q];
        }
#pragma unroll
        for (int off = 1; off < TPH; off <<= 1) {
            ps += __shfl_xor(ps, off);
            pd += __shfl_xor(pd, off);
        }
        if ((m_ & (TPH - 1)) == 0) {
            as_out[node * HEADS + head] = ps;
            ad_out[node * HEADS + head] = pd;
        }
    }
}

// ---------------- Layer-1 aggregation (flat, fp8 gather — R8 best) ------------
// One wave per node; no LDS/barriers. 8 groups x 8 lanes; group g owns edges
// rp+g+8k. Lane: head=l>>1, dims 16l..16l+15 (uint4 = 16 fp8).

__global__ __launch_bounds__(256) void agg1_kernel(
    const float* __restrict__ as1f, const float* __restrict__ ad1f,
    const uint* __restrict__ h1q, const int* __restrict__ rowptr,
    const int* __restrict__ csr, const float* __restrict__ b1,
    float* __restrict__ hout, int n)
{
    int t = threadIdx.x;
    int w = t >> 6, tw = t & 63;
    int g = tw >> 3, l = tw & 7;   // 8 groups x 8 lanes
    int head = l >> 1;
    int node = blockIdx.x * 4 + w;
    if (node >= n) return;

    float adh = ad1f[node * 4 + head];
    int rp = rowptr[node], re = rowptr[node + 1];

    float acc[16];
#pragma unroll
    for (int i = 0; i < 16; i++) acc[i] = 0.f;
    float den = 0.f;

#pragma unroll 2
    for (int e = rp + g; e < re; e += 8) {
        int s = csr[e];
        float a = as1f[s * 4 + head];
        uint4 u = *(const uint4*)(h1q + ((size_t)s << 5) + (l << 2));
        float ex = __expf(LRELU(a + adh));
        den += ex;
        uint ua[4] = {u.x, u.y, u.z, u.w};
#pragma unroll
        for (int j = 0; j < 4; j++) {
            auto p0 = __builtin_amdgcn_cvt_pk_f32_fp8(ua[j], false);
            auto p1 = __builtin_amdgcn_cvt_pk_f32_fp8(ua[j], true);
            acc[j*4+0] += ex * p0[0]; acc[j*4+1] += ex * p0[1];
            acc[j*4+2] += ex * p1[0]; acc[j*4+3] += ex * p1[1];
        }
    }

    if (g == 0) {   // self loop, counted once (pre-reduction)
        float a = as1f[node * 4 + head];
        float ex = __expf(LRELU(a + adh));
        den += ex;
        uint4 u = *(const uint4*)(h1q + ((size_t)node << 5) + (l << 2));
        uint ua[4] = {u.x, u.y, u.z, u.w};
#pragma unroll
        for (int j = 0; j < 4; j++) {
            auto p0 = __builtin_amdgcn_cvt_pk_f32_fp8(ua[j], false);
            auto p1 = __builtin_amdgcn_cvt_pk_f32_fp8(ua[j], true);
            acc[j*4+0] += ex * p0[0]; acc[j*4+1] += ex * p0[1];
            acc[j*4+2] += ex * p1[0]; acc[j*4+3] += ex * p1[1];
        }
    }

    // reduce across the 8 groups (lane-id bits 3,4,5)
#pragma unroll
    for (int i = 0; i < 16; i++) {
        acc[i] += __shfl_xor(acc[i], 8);
        acc[i] += __shfl_xor(acc[i], 16);
        acc[i] += __shfl_xor(acc[i], 32);
    }
    den += __shfl_xor(den, 8);
    den += __shfl_xor(den, 16);
    den += __shfl_xor(den, 32);

    if (g == 0) {
        float inv = 1.f / (den + 1e-16f);
        const float4* b4 = (const float4*)b1;
#pragma unroll
        for (int j = 0; j < 4; j++) {
            float4 bv = b4[(l << 2) + j];
            float4 o;
            o.x = fmaxf(acc[j*4+0] * inv + bv.x, 0.f);
            o.y = fmaxf(acc[j*4+1] * inv + bv.y, 0.f);
            o.z = fmaxf(acc[j*4+2] * inv + bv.z, 0.f);
            o.w = fmaxf(acc[j*4+3] * inv + bv.w, 0.f);
            ((float4*)hout)[(size_t)node * 32 + (l << 2) + j] = o;
        }
    }
}

// ---------------- Layer-2 aggregation (flat, fp8 gather, head-mean) -----------
// Same flat structure as agg1; lane l loads ONE uint = 4 fp8 dims (4l..4l+3);
// 8-lane group covers the 32B row; head = l>>2.

__global__ __launch_bounds__(256) void agg2_kernel(
    const float* __restrict__ as2f, const float* __restrict__ ad2f,
    const uint* __restrict__ h2q, const int* __restrict__ rowptr,
    const int* __restrict__ csr, const float* __restrict__ b2,
    float* __restrict__ hf, int n)
{
    int t = threadIdx.x;
    int w = t >> 6, tw = t & 63;
    int g = tw >> 3, l = tw & 7;
    int head = l >> 2;
    int node = blockIdx.x * 4 + w;
    if (node >= n) return;

    float adh = ad2f[node * 2 + head];
    int rp = rowptr[node], re = rowptr[node + 1];

    float acc[4] = {0.f, 0.f, 0.f, 0.f};
    float den = 0.f;

#pragma unroll 2
    for (int e = rp + g; e < re; e += 8) {
        int s = csr[e];
        float a = as2f[s * 2 + head];
        uint u = h2q[(size_t)s * 8 + l];
        float ex = __expf(LRELU(a + adh));
        den += ex;
        auto p0 = __builtin_amdgcn_cvt_pk_f32_fp8(u, false);
        auto p1 = __builtin_amdgcn_cvt_pk_f32_fp8(u, true);
        acc[0] += ex * p0[0]; acc[1] += ex * p0[1];
        acc[2] += ex * p1[0]; acc[3] += ex * p1[1];
    }

    if (g == 0) {   // self loop
        float a = as2f[node * 2 + head];
        float ex = __expf(LRELU(a + adh));
        den += ex;
        uint u = h2q[(size_t)node * 8 + l];
        auto p0 = __builtin_amdgcn_cvt_pk_f32_fp8(u, false);
        auto p1 = __builtin_amdgcn_cvt_pk_f32_fp8(u, true);
        acc[0] += ex * p0[0]; acc[1] += ex * p0[1];
        acc[2] += ex * p1[0]; acc[3] += ex * p1[1];
    }

#pragma unroll
    for (int i = 0; i < 4; i++) {
        acc[i] += __shfl_xor(acc[i], 8);
        acc[i] += __shfl_xor(acc[i], 16);
        acc[i] += __shfl_xor(acc[i], 32);
    }
    den += __shfl_xor(den, 8);
    den += __shfl_xor(den, 16);
    den += __shfl_xor(den, 32);

    float inv = 1.f / (den + 1e-16f);
    float v0 = acc[0] * inv, v1 = acc[1] * inv, v2 = acc[2] * inv, v3 = acc[3] * inv;
    // mean over heads: lane l (head0, dims 4l..) pairs with lane l^4 (head1)
    float o0 = 0.5f * (v0 + __shfl_xor(v0, 4));
    float o1 = 0.5f * (v1 + __shfl_xor(v1, 4));
    float o2 = 0.5f * (v2 + __shfl_xor(v2, 4));
    float o3 = 0.5f * (v3 + __shfl_xor(v3, 4));
    if (g == 0 && l < 4) {
        float4 o;
        o.x = o0 + b2[4*l+0]; o.y = o1 + b2[4*l+1];
        o.z = o2 + b2[4*l+2]; o.w = o3 + b2[4*l+3];
        *(float4*)(hf + (size_t)node * 16 + 4 * l) = o;
    }
}

// ---------------- Pooling + FC ----------------

__global__ __launch_bounds__(256) void pool_kernel(
    const float* __restrict__ hf, const int* __restrict__ batch,
    float* __restrict__ sums, float* __restrict__ counts, int n)
{
    int t = threadIdx.x;
    int d = t & 15, j = t >> 4;
    int base = blockIdx.x * 256 + j * 16;
    float run = 0.f, cnt = 0.f;
    int cg = -1;
    for (int i = 0; i < 16; ++i) {
        int nn = base + i;
        if (nn >= n) break;
        int g = batch[nn];
        if (g != cg) {
            if (cg >= 0) { atomicAdd(&sums[cg * 16 + d], run); if (d == 0) atomicAdd(&counts[cg], cnt); }
            cg = g; run = 0.f; cnt = 0.f;
        }
        run += hf[(size_t)nn * 16 + d];
        cnt += 1.f;
    }
    if (cg >= 0) { atomicAdd(&sums[cg * 16 + d], run); if (d == 0) atomicAdd(&counts[cg], cnt); }
}

__global__ void final_kernel(const float* __restrict__ sums, const float* __restrict__ counts,
                             const float* __restrict__ fcW, const float* __restrict__ fcb,
                             float* __restrict__ out, int G)
{
    int g = blockIdx.x * 64 + threadIdx.x;
    if (g < G) {
        float c = fmaxf(counts[g], 1.f);
        float s = 0.f;
        for (int dd = 0; dd < 16; ++dd) s += (sums[g * 16 + dd] / c) * fcW[dd];
        out[g] = s + fcb[0];
    }
}

// ---------------- launch ----------------

extern "C" void kernel_launch(void* const* d_in, const int* in_sizes, int n_in,
                              void* d_out, int out_size, void* d_ws, size_t ws_size,
                              hipStream_t stream)
{
    const float* x      = (const float*)d_in[0];
    const int*   ei     = (const int*)d_in[1];
    const int*   batch  = (const int*)d_in[2];
    const float* W1     = (const float*)d_in[3];
    const float* a_src1 = (const float*)d_in[4];
    const float* a_dst1 = (const float*)d_in[5];
    const float* b1     = (const float*)d_in[6];
    const float* W2     = (const float*)d_in[7];
    const float* a_src2 = (const float*)d_in[8];
    const float* a_dst2 = (const float*)d_in[9];
    const float* b2     = (const float*)d_in[10];
    const float* fcW    = (const float*)d_in[11];
    const float* fcb    = (const float*)d_in[12];
    float* out = (float*)d_out;

    int n = in_sizes[0] / 128;
    int E = in_sizes[1] / 2;
    int G = out_size;
    const int* srcA = ei;
    const int* dstA = ei + E;

    int nb = (n + (1 << CSR_SHIFT) - 1) >> CSR_SHIFT;
    int chunk = (E + CSR_NBLK - 1) / CSR_NBLK;

    char* p = (char*)d_ws;
    auto alloc = [&](size_t bytes) { char* r = p; p += (bytes + 255) & ~(size_t)255; return r; };
    int*   blockCntT  = (int*)alloc((size_t)nb * CSR_NBLK * 4);
    int*   tot        = (int*)alloc((size_t)nb * 4);
    int*   bucketBase = (int*)alloc((size_t)(nb + 1) * 4);
    int*   rowptr     = (int*)alloc((size_t)(n + 1) * 4);
    int*   csr        = (int*)alloc((size_t)E * 4);
    uint*  h1q        = (uint*)alloc((size_t)n * 32 * 4);    // fp8 x4 per uint (128 dims)
    float* as1        = (float*)alloc((size_t)n * 16);
    float* ad1        = (float*)alloc((size_t)n * 16);
    float* hrelu      = (float*)alloc((size_t)n * 128 * 4);  // fp32
    uint*  h2q        = (uint*)alloc((size_t)n * 8 * 4);     // fp8 x4 per uint (32 dims)
    float* as2        = (float*)alloc((size_t)n * 8);
    float* ad2        = (float*)alloc((size_t)n * 8);
    float* hf         = (float*)alloc((size_t)n * 16 * 4);
    float* sums       = (float*)alloc((size_t)(G * 16 + G) * 4);
    float* counts     = sums + G * 16;

    // edge staging buffer aliases hrelu; consumed by local_csr before agg1 writes.
    uint* ebuf = (uint*)hrelu;

    hipMemsetAsync(sums, 0, (size_t)(G * 16 + G) * 4, stream);

    bucket_count_kernel<<<CSR_NBLK, 256, 0, stream>>>(dstA, E, chunk, nb, blockCntT);
    row_scan_kernel<<<nb, 512, 0, stream>>>(blockCntT, tot);
    total_scan_kernel<<<1, 1024, 0, stream>>>(tot, nb, bucketBase);
    bucket_scatter_kernel<<<CSR_NBLK, 256, 0, stream>>>(srcA, dstA, E, chunk, nb,
                                                        blockCntT, bucketBase, ebuf);
    local_csr_kernel<<<nb, 256, 0, stream>>>(ebuf, bucketBase, n, E, rowptr, csr);

    int gb = (n + 63) / 64;   // NPT=2: 64 nodes per block
    gemm_alpha_kernel<128, 4><<<gb, 256, 0, stream>>>(x, W1, a_src1, a_dst1, h1q, as1, ad1, n);
    agg1_kernel<<<(n + 3) / 4, 256, 0, stream>>>(as1, ad1, h1q, rowptr, csr, b1, hrelu, n);
    gemm_alpha_kernel<32, 2><<<gb, 256, 0, stream>>>(hrelu, W2, a_src2, a_dst2, h2q, as2, ad2, n);
    agg2_kernel<<<(n + 3) / 4, 256, 0, stream>>>(as2, ad2, h2q, rowptr, csr, b2, hf, n);
    pool_kernel<<<(n + 255) / 256, 256, 0, stream>>>(hf, batch, sums, counts, n);
    final_kernel<<<1, 64, 0, stream>>>(sums, counts, fcW, fcb, out, G);
}

// Round 16
// 183.328 us; speedup vs baseline: 1.3903x; 1.0582x over previous
//
#include <hip/hip_runtime.h>

#define LRELU(x) ((x) > 0.f ? (x) : 0.2f*(x))
typedef unsigned int uint;
typedef unsigned short ushort;
typedef _Float16 half2_t __attribute__((ext_vector_type(2)));

__device__ inline ushort f2bf(float f) {
    union { float f; unsigned u; } v; v.f = f;
    unsigned r = v.u + 0x7FFF + ((v.u >> 16) & 1);
    return (ushort)(r >> 16);
}
__device__ inline uint packbf(float a, float b) {
    return (uint)f2bf(a) | ((uint)f2bf(b) << 16);
}
__device__ inline float bflo(uint u){ union{uint u; float f;}v; v.u = u<<16; return v.f; }
__device__ inline float bfhi(uint u){ union{uint u; float f;}v; v.u = u & 0xFFFF0000u; return v.f; }
__device__ inline half2_t u2h(uint u){ union{uint u; half2_t h;}v; v.u=u; return v.h; }
__device__ inline uint h2u(half2_t h){ union{half2_t h; uint u;}v; v.h=h; return v.u; }
__device__ inline uint packh(float a, float b){
    half2_t h; h.x = (_Float16)a; h.y = (_Float16)b; return h2u(h);
}

// ---------------- CSR build: atomic-free two-level bucket sort ----------------
// ebuf entries packed: (src << 7) | (dst & 127)
// Scan kept as TWO kernels deliberately — fused last-block version needs
// agent-scope __threadfence() = L2 writeback on multi-XCD gfx950 (~60us, R10).
// chunk is rounded to a multiple of 4 so int4 edge loads are aligned/in-bounds
// (E itself is a multiple of 4).

#define CSR_SHIFT 7
#define CSR_NBLK  512

__global__ __launch_bounds__(256) void bucket_count_kernel(
    const int* __restrict__ dst, int E, int chunk, int nb,
    int* __restrict__ blockCntT)
{
    __shared__ int cnt[1024];
    int t = threadIdx.x, k = blockIdx.x;
    for (int i = t; i < nb; i += 256) cnt[i] = 0;
    __syncthreads();
    int e0 = k * chunk, e1 = min(e0 + chunk, E);
    for (int e = e0 + t * 4; e < e1; e += 1024) {
        int4 d4 = *(const int4*)(dst + e);
        atomicAdd(&cnt[d4.x >> CSR_SHIFT], 1);
        atomicAdd(&cnt[d4.y >> CSR_SHIFT], 1);
        atomicAdd(&cnt[d4.z >> CSR_SHIFT], 1);
        atomicAdd(&cnt[d4.w >> CSR_SHIFT], 1);
    }
    __syncthreads();
    for (int b = t; b < nb; b += 256)
        blockCntT[b * CSR_NBLK + k] = cnt[b];
}

__global__ __launch_bounds__(512) void row_scan_kernel(
    int* __restrict__ blockCntT, int* __restrict__ tot)
{
    __shared__ int sm[512];
    int b = blockIdx.x, t = threadIdx.x;
    int* row = blockCntT + b * CSR_NBLK;
    int v = row[t];
    sm[t] = v;
    __syncthreads();
    for (int off = 1; off < 512; off <<= 1) {
        int u = (t >= off) ? sm[t - off] : 0;
        __syncthreads(); sm[t] += u; __syncthreads();
    }
    row[t] = sm[t] - v;            // exclusive within bucket
    if (t == 511) tot[b] = sm[511];
}

__global__ __launch_bounds__(1024) void total_scan_kernel(
    const int* __restrict__ tot, int nb, int* __restrict__ bucketBase)
{
    __shared__ int sm[1024];
    int t = threadIdx.x;
    int v = (t < nb) ? tot[t] : 0;
    sm[t] = v;
    __syncthreads();
    for (int off = 1; off < 1024; off <<= 1) {
        int u = (t >= off) ? sm[t - off] : 0;
        __syncthreads(); sm[t] += u; __syncthreads();
    }
    if (t < nb) bucketBase[t] = sm[t] - v;
    if (t == 1023) bucketBase[nb] = sm[1023];
}

__global__ __launch_bounds__(256) void bucket_scatter_kernel(
    const int* __restrict__ src, const int* __restrict__ dst, int E, int chunk, int nb,
    const int* __restrict__ blockCntT, const int* __restrict__ bucketBase,
    uint* __restrict__ ebuf)
{
    __shared__ int cur[1024];
    int t = threadIdx.x, k = blockIdx.x;
    for (int b = t; b < nb; b += 256)
        cur[b] = bucketBase[b] + blockCntT[b * CSR_NBLK + k];
    __syncthreads();
    int e0 = k * chunk, e1 = min(e0 + chunk, E);
    for (int e = e0 + t * 4; e < e1; e += 1024) {
        int4 d4 = *(const int4*)(dst + e);
        int4 s4 = *(const int4*)(src + e);
        int p0 = atomicAdd(&cur[d4.x >> CSR_SHIFT], 1);
        ebuf[p0] = ((uint)s4.x << 7) | (uint)(d4.x & 127);
        int p1 = atomicAdd(&cur[d4.y >> CSR_SHIFT], 1);
        ebuf[p1] = ((uint)s4.y << 7) | (uint)(d4.y & 127);
        int p2 = atomicAdd(&cur[d4.z >> CSR_SHIFT], 1);
        ebuf[p2] = ((uint)s4.z << 7) | (uint)(d4.z & 127);
        int p3 = atomicAdd(&cur[d4.w >> CSR_SHIFT], 1);
        ebuf[p3] = ((uint)s4.w << 7) | (uint)(d4.w & 127);
    }
}

__global__ __launch_bounds__(256) void local_csr_kernel(
    const uint* __restrict__ ebuf, const int* __restrict__ bucketBase,
    int n, int E, int* __restrict__ rowptr, int* __restrict__ csr)
{
    __shared__ int lbase[1 << CSR_SHIFT];
    __shared__ int lcur[1 << CSR_SHIFT];
    __shared__ int ldeg[1 << CSR_SHIFT];
    int b = blockIdx.x, t = threadIdx.x;
    int n0 = b << CSR_SHIFT;
    int base = bucketBase[b], end = bucketBase[b + 1];
    if (t < (1 << CSR_SHIFT)) ldeg[t] = 0;
    __syncthreads();
    for (int e = base + t; e < end; e += 256)
        atomicAdd(&ldeg[ebuf[e] & 127], 1);
    __syncthreads();
    if (t == 0) {
        int run = base;
        for (int i = 0; i < (1 << CSR_SHIFT); ++i) {
            lbase[i] = run; lcur[i] = run; run += ldeg[i];
        }
    }
    __syncthreads();
    int node = n0 + t;
    if (t < (1 << CSR_SHIFT) && node < n) rowptr[node] = lbase[t];
    if (b == 0 && t == 0) rowptr[n] = E;
    for (int e = base + t; e < end; e += 256) {
        uint ed = ebuf[e];
        int pos = atomicAdd(&lcur[ed & 127], 1);
        csr[pos] = (int)(ed >> 7);
    }
}

// ---------------- GEMM + fused alpha dots (f16 dot2, swizzled LDS) -------------
// W staged in LDS as f16 K-PAIRS; bit-rotation swizzle for COLS=128 keeps the
// 8 col-threads on 8 consecutive uint4 (=all 32 banks) per j. NPT=2.
// XBF16: input rows are bf16-packed uints (n x 64). Output: fp8 e4m3 rows.

template<int COLS, int HEADS, bool XBF16>
__global__ __launch_bounds__(256) void gemm_alpha_kernel(
    const void* __restrict__ xin, const float* __restrict__ W,
    const float* __restrict__ a_src, const float* __restrict__ a_dst,
    uint* __restrict__ hq, float* __restrict__ as_out,
    float* __restrict__ ad_out, int n)
{
    constexpr int K = 128;
    constexpr int K2 = K / 2;
    constexpr int CPT = COLS / 8;       // cols per thread (16 or 4)
    constexpr int NPT = 2;
    constexpr int DIM = COLS / HEADS;
    constexpr int TPH = DIM / CPT;      // 2 or 4
    constexpr int NSLOT4 = COLS / 4;    // uint4 slots per k2-row
    __shared__ uint WLH[K2 * COLS];     // f16x2 per uint

    int t = threadIdx.x;
    for (int sid = t; sid < K2 * NSLOT4; sid += 256) {
        int k2 = sid / NSLOT4, s = sid % NSLOT4;
        int c = s * 4;
        float4 w0 = *(const float4*)(W + (2 * k2) * COLS + c);
        float4 w1 = *(const float4*)(W + (2 * k2 + 1) * COLS + c);
        uint4 u;
        u.x = packh(w0.x, w1.x);
        u.y = packh(w0.y, w1.y);
        u.z = packh(w0.z, w1.z);
        u.w = packh(w0.w, w1.w);
        int p = (COLS == 128) ? (((s & 3) << 3) | (s >> 2)) : s;   // bijective swizzle
        ((uint4*)WLH)[k2 * NSLOT4 + p] = u;
    }
    __syncthreads();

    int m_ = t & 7;
    int node0 = blockIdx.x * (32 * NPT) + (t >> 3) * NPT;
    if (node0 >= n) return;
    int c0 = m_ * CPT;

    size_t rows[NPT];
#pragma unroll
    for (int i = 0; i < NPT; i++) rows[i] = (size_t)min(node0 + i, n - 1);

    float acc[NPT][CPT];
#pragma unroll
    for (int i = 0; i < NPT; i++)
#pragma unroll
        for (int q = 0; q < CPT; q++) acc[i][q] = 0.f;

    for (int k4 = 0; k4 < K; k4 += 4) {     // 4 k-values = 2 k2-pairs per iter
        half2_t xp[NPT][2];
#pragma unroll
        for (int i = 0; i < NPT; i++) {
            if constexpr (XBF16) {
                uint2 u = *(const uint2*)((const uint*)xin + rows[i] * 64 + (k4 >> 1));
                half2_t h0; h0.x = (_Float16)bflo(u.x); h0.y = (_Float16)bfhi(u.x);
                half2_t h1; h1.x = (_Float16)bflo(u.y); h1.y = (_Float16)bfhi(u.y);
                xp[i][0] = h0; xp[i][1] = h1;
            } else {
                float4 v = *(const float4*)((const float*)xin + rows[i] * K + k4);
                half2_t h0; h0.x = (_Float16)v.x; h0.y = (_Float16)v.y;
                half2_t h1; h1.x = (_Float16)v.z; h1.y = (_Float16)v.w;
                xp[i][0] = h0; xp[i][1] = h1;
            }
        }
#pragma unroll
        for (int p = 0; p < 2; p++) {
            int k2 = (k4 >> 1) + p;
#pragma unroll
            for (int j = 0; j < CPT / 4; j++) {
                int slot = (COLS == 128) ? ((j << 3) | m_) : m_;
                uint4 wq = ((const uint4*)WLH)[k2 * NSLOT4 + slot];
                half2_t w0 = u2h(wq.x), w1 = u2h(wq.y), w2 = u2h(wq.z), w3 = u2h(wq.w);
#pragma unroll
                for (int i = 0; i < NPT; i++) {
                    half2_t xv = xp[i][p];
                    acc[i][j*4+0] = __builtin_amdgcn_fdot2(xv, w0, acc[i][j*4+0], false);
                    acc[i][j*4+1] = __builtin_amdgcn_fdot2(xv, w1, acc[i][j*4+1], false);
                    acc[i][j*4+2] = __builtin_amdgcn_fdot2(xv, w2, acc[i][j*4+2], false);
                    acc[i][j*4+3] = __builtin_amdgcn_fdot2(xv, w3, acc[i][j*4+3], false);
                }
            }
        }
    }

    int head = c0 / DIM, lc = c0 - head * DIM;
    float asc[CPT], adc[CPT];
#pragma unroll
    for (int q = 0; q < CPT; q++) {
        asc[q] = a_src[head * DIM + lc + q];
        adc[q] = a_dst[head * DIM + lc + q];
    }

#pragma unroll
    for (int i = 0; i < NPT; i++) {
        int node = node0 + i;
        if (node >= n) break;
        if constexpr (COLS == 128) {
            uint wds[4];
#pragma unroll
            for (int j = 0; j < 4; j++) {
                int u = 0;
                u = __builtin_amdgcn_cvt_pk_fp8_f32(acc[i][j*4+0], acc[i][j*4+1], u, false);
                u = __builtin_amdgcn_cvt_pk_fp8_f32(acc[i][j*4+2], acc[i][j*4+3], u, true);
                wds[j] = (uint)u;
            }
            *(uint4*)(hq + (size_t)node * 32 + m_ * 4) = make_uint4(wds[0], wds[1], wds[2], wds[3]);
        } else {
            // fp8 row: 8 uints per node (32 dims), one uint per col-thread
            int u = 0;
            u = __builtin_amdgcn_cvt_pk_fp8_f32(acc[i][0], acc[i][1], u, false);
            u = __builtin_amdgcn_cvt_pk_fp8_f32(acc[i][2], acc[i][3], u, true);
            hq[(size_t)node * 8 + m_] = (uint)u;
        }
        float ps = 0.f, pd = 0.f;
#pragma unroll
        for (int q = 0; q < CPT; q++) {
            ps += acc[i][q] * asc[q];
            pd += acc[i][q] * adc[q];
        }
#pragma unroll
        for (int off = 1; off < TPH; off <<= 1) {
            ps += __shfl_xor(ps, off);
            pd += __shfl_xor(pd, off);
        }
        if ((m_ & (TPH - 1)) == 0) {
            as_out[node * HEADS + head] = ps;
            ad_out[node * HEADS + head] = pd;
        }
    }
}

// ---------------- Layer-1 aggregation (flat, fp8 gather — R8 structure) -------
// One wave per node; no LDS/barriers. 8 groups x 8 lanes; group g owns edges
// rp+g+8k. Lane: head=l>>1, dims 16l..16l+15 (uint4 = 16 fp8).
// Output hrelu in bf16 (uint i holds dims 2i,2i+1; low half = even dim).

__global__ __launch_bounds__(256) void agg1_kernel(
    const float* __restrict__ as1f, const float* __restrict__ ad1f,
    const uint* __restrict__ h1q, const int* __restrict__ rowptr,
    const int* __restrict__ csr, const float* __restrict__ b1,
    uint* __restrict__ hrelu, int n)
{
    int t = threadIdx.x;
    int w = t >> 6, tw = t & 63;
    int g = tw >> 3, l = tw & 7;   // 8 groups x 8 lanes
    int head = l >> 1;
    int node = blockIdx.x * 4 + w;
    if (node >= n) return;

    float adh = ad1f[node * 4 + head];
    int rp = rowptr[node], re = rowptr[node + 1];

    float acc[16];
#pragma unroll
    for (int i = 0; i < 16; i++) acc[i] = 0.f;
    float den = 0.f;

#pragma unroll 2
    for (int e = rp + g; e < re; e += 8) {
        int s = csr[e];
        float a = as1f[s * 4 + head];
        uint4 u = *(const uint4*)(h1q + ((size_t)s << 5) + (l << 2));
        float ex = __expf(LRELU(a + adh));
        den += ex;
        uint ua[4] = {u.x, u.y, u.z, u.w};
#pragma unroll
        for (int j = 0; j < 4; j++) {
            auto p0 = __builtin_amdgcn_cvt_pk_f32_fp8(ua[j], false);
            auto p1 = __builtin_amdgcn_cvt_pk_f32_fp8(ua[j], true);
            acc[j*4+0] += ex * p0[0]; acc[j*4+1] += ex * p0[1];
            acc[j*4+2] += ex * p1[0]; acc[j*4+3] += ex * p1[1];
        }
    }

    if (g == 0) {   // self loop, counted once (pre-reduction)
        float a = as1f[node * 4 + head];
        float ex = __expf(LRELU(a + adh));
        den += ex;
        uint4 u = *(const uint4*)(h1q + ((size_t)node << 5) + (l << 2));
        uint ua[4] = {u.x, u.y, u.z, u.w};
#pragma unroll
        for (int j = 0; j < 4; j++) {
            auto p0 = __builtin_amdgcn_cvt_pk_f32_fp8(ua[j], false);
            auto p1 = __builtin_amdgcn_cvt_pk_f32_fp8(ua[j], true);
            acc[j*4+0] += ex * p0[0]; acc[j*4+1] += ex * p0[1];
            acc[j*4+2] += ex * p1[0]; acc[j*4+3] += ex * p1[1];
        }
    }

    // reduce across the 8 groups (lane-id bits 3,4,5)
#pragma unroll
    for (int i = 0; i < 16; i++) {
        acc[i] += __shfl_xor(acc[i], 8);
        acc[i] += __shfl_xor(acc[i], 16);
        acc[i] += __shfl_xor(acc[i], 32);
    }
    den += __shfl_xor(den, 8);
    den += __shfl_xor(den, 16);
    den += __shfl_xor(den, 32);

    if (g == 0) {
        float inv = 1.f / (den + 1e-16f);
        uint o[8];
#pragma unroll
        for (int j = 0; j < 4; j++) {
            float v0 = fmaxf(acc[j*4+0] * inv + b1[16*l + 4*j + 0], 0.f);
            float v1 = fmaxf(acc[j*4+1] * inv + b1[16*l + 4*j + 1], 0.f);
            float v2 = fmaxf(acc[j*4+2] * inv + b1[16*l + 4*j + 2], 0.f);
            float v3 = fmaxf(acc[j*4+3] * inv + b1[16*l + 4*j + 3], 0.f);
            o[2*j]   = packbf(v0, v1);
            o[2*j+1] = packbf(v2, v3);
        }
        uint* hp = hrelu + (size_t)node * 64 + l * 8;
        *(uint4*)hp       = make_uint4(o[0], o[1], o[2], o[3]);
        *(uint4*)(hp + 4) = make_uint4(o[4], o[5], o[6], o[7]);
    }
}

// ---------------- Layer-2 aggregation (flat, fp8 gather, head-mean) -----------
// Lane l loads ONE uint = 4 fp8 dims (4l..4l+3); 8-lane group covers the 32B
// row; head = l>>2.

__global__ __launch_bounds__(256) void agg2_kernel(
    const float* __restrict__ as2f, const float* __restrict__ ad2f,
    const uint* __restrict__ h2q, const int* __restrict__ rowptr,
    const int* __restrict__ csr, const float* __restrict__ b2,
    float* __restrict__ hf, int n)
{
    int t = threadIdx.x;
    int w = t >> 6, tw = t & 63;
    int g = tw >> 3, l = tw & 7;
    int head = l >> 2;
    int node = blockIdx.x * 4 + w;
    if (node >= n) return;

    float adh = ad2f[node * 2 + head];
    int rp = rowptr[node], re = rowptr[node + 1];

    float acc[4] = {0.f, 0.f, 0.f, 0.f};
    float den = 0.f;

#pragma unroll 2
    for (int e = rp + g; e < re; e += 8) {
        int s = csr[e];
        float a = as2f[s * 2 + head];
        uint u = h2q[(size_t)s * 8 + l];
        float ex = __expf(LRELU(a + adh));
        den += ex;
        auto p0 = __builtin_amdgcn_cvt_pk_f32_fp8(u, false);
        auto p1 = __builtin_amdgcn_cvt_pk_f32_fp8(u, true);
        acc[0] += ex * p0[0]; acc[1] += ex * p0[1];
        acc[2] += ex * p1[0]; acc[3] += ex * p1[1];
    }

    if (g == 0) {   // self loop
        float a = as2f[node * 2 + head];
        float ex = __expf(LRELU(a + adh));
        den += ex;
        uint u = h2q[(size_t)node * 8 + l];
        auto p0 = __builtin_amdgcn_cvt_pk_f32_fp8(u, false);
        auto p1 = __builtin_amdgcn_cvt_pk_f32_fp8(u, true);
        acc[0] += ex * p0[0]; acc[1] += ex * p0[1];
        acc[2] += ex * p1[0]; acc[3] += ex * p1[1];
    }

#pragma unroll
    for (int i = 0; i < 4; i++) {
        acc[i] += __shfl_xor(acc[i], 8);
        acc[i] += __shfl_xor(acc[i], 16);
        acc[i] += __shfl_xor(acc[i], 32);
    }
    den += __shfl_xor(den, 8);
    den += __shfl_xor(den, 16);
    den += __shfl_xor(den, 32);

    float inv = 1.f / (den + 1e-16f);
    float v0 = acc[0] * inv, v1 = acc[1] * inv, v2 = acc[2] * inv, v3 = acc[3] * inv;
    // mean over heads: lane l (head0, dims 4l..) pairs with lane l^4 (head1)
    float o0 = 0.5f * (v0 + __shfl_xor(v0, 4));
    float o1 = 0.5f * (v1 + __shfl_xor(v1, 4));
    float o2 = 0.5f * (v2 + __shfl_xor(v2, 4));
    float o3 = 0.5f * (v3 + __shfl_xor(v3, 4));
    if (g == 0 && l < 4) {
        float4 o;
        o.x = o0 + b2[4*l+0]; o.y = o1 + b2[4*l+1];
        o.z = o2 + b2[4*l+2]; o.w = o3 + b2[4*l+3];
        *(float4*)(hf + (size_t)node * 16 + 4 * l) = o;
    }
}

// ---------------- Pooling + FC ----------------

__global__ __launch_bounds__(256) void pool_kernel(
    const float* __restrict__ hf, const int* __restrict__ batch,
    float* __restrict__ sums, float* __restrict__ counts, int n)
{
    int t = threadIdx.x;
    int d = t & 15, j = t >> 4;
    int base = blockIdx.x * 256 + j * 16;
    float run = 0.f, cnt = 0.f;
    int cg = -1;
    for (int i = 0; i < 16; ++i) {
        int nn = base + i;
        if (nn >= n) break;
        int g = batch[nn];
        if (g != cg) {
            if (cg >= 0) { atomicAdd(&sums[cg * 16 + d], run); if (d == 0) atomicAdd(&counts[cg], cnt); }
            cg = g; run = 0.f; cnt = 0.f;
        }
        run += hf[(size_t)nn * 16 + d];
        cnt += 1.f;
    }
    if (cg >= 0) { atomicAdd(&sums[cg * 16 + d], run); if (d == 0) atomicAdd(&counts[cg], cnt); }
}

__global__ void final_kernel(const float* __restrict__ sums, const float* __restrict__ counts,
                             const float* __restrict__ fcW, const float* __restrict__ fcb,
                             float* __restrict__ out, int G)
{
    int g = blockIdx.x * 64 + threadIdx.x;
    if (g < G) {
        float c = fmaxf(counts[g], 1.f);
        float s = 0.f;
        for (int dd = 0; dd < 16; ++dd) s += (sums[g * 16 + dd] / c) * fcW[dd];
        out[g] = s + fcb[0];
    }
}

// ---------------- launch ----------------

extern "C" void kernel_launch(void* const* d_in, const int* in_sizes, int n_in,
                              void* d_out, int out_size, void* d_ws, size_t ws_size,
                              hipStream_t stream)
{
    const float* x      = (const float*)d_in[0];
    const int*   ei     = (const int*)d_in[1];
    const int*   batch  = (const int*)d_in[2];
    const float* W1     = (const float*)d_in[3];
    const float* a_src1 = (const float*)d_in[4];
    const float* a_dst1 = (const float*)d_in[5];
    const float* b1     = (const float*)d_in[6];
    const float* W2     = (const float*)d_in[7];
    const float* a_src2 = (const float*)d_in[8];
    const float* a_dst2 = (const float*)d_in[9];
    const float* b2     = (const float*)d_in[10];
    const float* fcW    = (const float*)d_in[11];
    const float* fcb    = (const float*)d_in[12];
    float* out = (float*)d_out;

    int n = in_sizes[0] / 128;
    int E = in_sizes[1] / 2;
    int G = out_size;
    const int* srcA = ei;
    const int* dstA = ei + E;

    int nb = (n + (1 << CSR_SHIFT) - 1) >> CSR_SHIFT;
    int chunk = (((E + CSR_NBLK - 1) / CSR_NBLK) + 3) & ~3;   // x4 for int4 loads

    char* p = (char*)d_ws;
    auto alloc = [&](size_t bytes) { char* r = p; p += (bytes + 255) & ~(size_t)255; return r; };
    int*   blockCntT  = (int*)alloc((size_t)nb * CSR_NBLK * 4);
    int*   tot        = (int*)alloc((size_t)nb * 4);
    int*   bucketBase = (int*)alloc((size_t)(nb + 1) * 4);
    int*   rowptr     = (int*)alloc((size_t)(n + 1) * 4);
    int*   csr        = (int*)alloc((size_t)E * 4);
    uint*  h1q        = (uint*)alloc((size_t)n * 32 * 4);    // fp8 x4 per uint (128 dims)
    float* as1        = (float*)alloc((size_t)n * 16);
    float* ad1        = (float*)alloc((size_t)n * 16);
    uint*  hrelu      = (uint*)alloc((size_t)n * 64 * 4);    // bf16 x2 per uint (128 dims)
    uint*  h2q        = (uint*)alloc((size_t)n * 8 * 4);     // fp8 x4 per uint (32 dims)
    float* as2        = (float*)alloc((size_t)n * 8);
    float* ad2        = (float*)alloc((size_t)n * 8);
    float* hf         = (float*)alloc((size_t)n * 16 * 4);
    float* sums       = (float*)alloc((size_t)(G * 16 + G) * 4);
    float* counts     = sums + G * 16;

    // edge staging buffer aliases hrelu (E*4 = 6.6MB <= n*64*4 = 12.8MB);
    // fully consumed by local_csr_kernel before agg1 writes hrelu.
    uint* ebuf = (uint*)hrelu;

    hipMemsetAsync(sums, 0, (size_t)(G * 16 + G) * 4, stream);

    bucket_count_kernel<<<CSR_NBLK, 256, 0, stream>>>(dstA, E, chunk, nb, blockCntT);
    row_scan_kernel<<<nb, 512, 0, stream>>>(blockCntT, tot);
    total_scan_kernel<<<1, 1024, 0, stream>>>(tot, nb, bucketBase);
    bucket_scatter_kernel<<<CSR_NBLK, 256, 0, stream>>>(srcA, dstA, E, chunk, nb,
                                                        blockCntT, bucketBase, ebuf);
    local_csr_kernel<<<nb, 256, 0, stream>>>(ebuf, bucketBase, n, E, rowptr, csr);

    int gb = (n + 63) / 64;   // NPT=2: 64 nodes per block
    gemm_alpha_kernel<128, 4, false><<<gb, 256, 0, stream>>>(x, W1, a_src1, a_dst1,
                                                             h1q, as1, ad1, n);
    agg1_kernel<<<(n + 3) / 4, 256, 0, stream>>>(as1, ad1, h1q, rowptr, csr, b1, hrelu, n);
    gemm_alpha_kernel<32, 2, true><<<gb, 256, 0, stream>>>(hrelu, W2, a_src2, a_dst2,
                                                           h2q, as2, ad2, n);
    agg2_kernel<<<(n + 3) / 4, 256, 0, stream>>>(as2, ad2, h2q, rowptr, csr, b2, hf, n);
    pool_kernel<<<(n + 255) / 256, 256, 0, stream>>>(hf, batch, sums, counts, n);
    final_kernel<<<1, 64, 0, stream>>>(sums, counts, fcW, fcb, out, G);
}